// Round 1
// baseline (978.985 us; speedup 1.0000x reference)
//
#include <hip/hip_runtime.h>
#include <hip/hip_bf16.h>
#include <math.h>

#define NN 4096
#define MM 1024
#define BANDW 511
#define BANDP 512

typedef float f4v __attribute__((ext_vector_type(4)));

// ---------------- fp32 GEMM: C[M x N] = A[M x K] @ B[K x N] (+bias) --------
// BM=128, BN=64, BK=16; 256 threads; per-thread 8x4 (rows split 4+4 @64)
__global__ __launch_bounds__(256, 2)
void gemm_f32(const float* __restrict__ A, const float* __restrict__ B,
              const float* __restrict__ bias, float* __restrict__ C,
              int M, int N, int K)
{
    __shared__ float As[2][16][132];
    __shared__ float Bs[2][16][64];

    const int tid = threadIdx.x;
    const int m0 = blockIdx.y << 7;
    const int n0 = blockIdx.x << 6;
    const int tm = tid >> 4;
    const int tn = tid & 15;

    const int ar = tid >> 2;          // 0..63
    const int aq = (tid & 3) << 2;    // 0,4,8,12
    const int bk = tid >> 4;          // 0..15
    const int bq = (tid & 15) << 2;   // 0..60

    const float* Ap0 = A + (size_t)(m0 + ar) * K + aq;
    const float* Ap1 = A + (size_t)(m0 + ar + 64) * K + aq;
    const float* Bp  = B + (size_t)bk * N + n0 + bq;

    f4v pa0 = *(const f4v*)(Ap0);
    f4v pa1 = *(const f4v*)(Ap1);
    f4v pb  = *(const f4v*)(Bp);

    float acc0[4][4] = {};
    float acc1[4][4] = {};

    #pragma unroll
    for (int l = 0; l < 4; ++l) {
        As[0][aq + l][ar]      = pa0[l];
        As[0][aq + l][ar + 64] = pa1[l];
    }
    *(f4v*)&Bs[0][bk][bq] = pb;
    __syncthreads();

    const int NKT = K >> 4;
    for (int kt = 0; kt < NKT; ++kt) {
        const int cur = kt & 1;
        if (kt + 1 < NKT) {
            const int k0 = (kt + 1) << 4;
            pa0 = *(const f4v*)(Ap0 + k0);
            pa1 = *(const f4v*)(Ap1 + k0);
            pb  = *(const f4v*)(Bp + (size_t)k0 * N);
        }
        #pragma unroll
        for (int kk = 0; kk < 16; ++kk) {
            f4v a0 = *(const f4v*)&As[cur][kk][tm << 2];
            f4v a1 = *(const f4v*)&As[cur][kk][64 + (tm << 2)];
            f4v b  = *(const f4v*)&Bs[cur][kk][tn << 2];
            #pragma unroll
            for (int r = 0; r < 4; ++r) {
                #pragma unroll
                for (int c = 0; c < 4; ++c) {
                    acc0[r][c] += a0[r] * b[c];
                    acc1[r][c] += a1[r] * b[c];
                }
            }
        }
        if (kt + 1 < NKT) {
            const int nxt = cur ^ 1;
            #pragma unroll
            for (int l = 0; l < 4; ++l) {
                As[nxt][aq + l][ar]      = pa0[l];
                As[nxt][aq + l][ar + 64] = pa1[l];
            }
            *(f4v*)&Bs[nxt][bk][bq] = pb;
        }
        __syncthreads();
    }

    f4v bv = {0.f, 0.f, 0.f, 0.f};
    if (bias) bv = *(const f4v*)&bias[n0 + (tn << 2)];

    #pragma unroll
    for (int r = 0; r < 4; ++r) {
        f4v o0, o1;
        #pragma unroll
        for (int c = 0; c < 4; ++c) { o0[c] = acc0[r][c] + bv[c]; o1[c] = acc1[r][c] + bv[c]; }
        *(f4v*)&C[(size_t)(m0 + (tm << 2) + r) * N + n0 + (tn << 2)]      = o0;
        *(f4v*)&C[(size_t)(m0 + 64 + (tm << 2) + r) * N + n0 + (tn << 2)] = o1;
    }
}

// ---------------- bilinear grid sample (matches torch align_corners=True) ----
__global__ __launch_bounds__(256)
void grid_sample_k(const float* __restrict__ x, const float* __restrict__ ofx,
                   const float* __restrict__ ofy, float* __restrict__ xn)
{
    const int i = blockIdx.x;
    const int tid = threadIdx.x;
    const int j4 = tid << 2;

    f4v fx = *(const f4v*)&ofx[(size_t)i * MM + j4];
    f4v fy = *(const f4v*)&ofy[(size_t)i * MM + j4];
    f4v out;

    const float gxb = (2.0f * (float)i) / (float)NN - 1.0f;

    #pragma unroll
    for (int l = 0; l < 4; ++l) {
        const int j = j4 + l;
        float gx = gxb + fx[l];
        gx = fminf(fmaxf(gx, -1.0f), 1.0f);
        float gy = (2.0f * (float)j) / (float)MM - 1.0f + fy[l];
        gy = fminf(fmaxf(gy, -1.0f), 1.0f);

        const float ixf = (gx + 1.0f) * 511.5f;    // (W-1)*0.5
        const float iyf = (gy + 1.0f) * 2047.5f;   // (H-1)*0.5
        const float ix0 = floorf(ixf);
        const float iy0 = floorf(iyf);
        const float wx = ixf - ix0;
        const float wy = iyf - iy0;
        int ix0i = (int)ix0; ix0i = max(0, min(ix0i, MM - 1));
        int iy0i = (int)iy0; iy0i = max(0, min(iy0i, NN - 1));
        const int ix1i = min(ix0i + 1, MM - 1);
        const int iy1i = min(iy0i + 1, NN - 1);

        const float* r0 = x + (size_t)iy0i * MM;
        const float* r1 = x + (size_t)iy1i * MM;
        const float v00 = r0[ix0i], v01 = r0[ix1i];
        const float v10 = r1[ix0i], v11 = r1[ix1i];
        out[l] = (1.0f - wy) * ((1.0f - wx) * v00 + wx * v01)
               + wy * ((1.0f - wx) * v10 + wx * v11);
    }
    *(f4v*)&xn[(size_t)i * MM + j4] = out;
}

// ---------------- banded logits: band[i][c] = 0.06*dot(Q[i],K[j]), c=j-i+255 --
__global__ __launch_bounds__(256, 2)
void band_logits(const float* __restrict__ Q, const float* __restrict__ Kmat,
                 float* __restrict__ band)
{
    __shared__ float Qs[2][16][68];
    __shared__ float Ks[2][16][68];

    const int tid = threadIdx.x;
    const int i0 = blockIdx.y << 6;
    const int j0 = i0 - 256 + (blockIdx.x << 6);
    const int tm = tid >> 4;
    const int tn = tid & 15;
    const int lr = tid >> 2;
    const int lq = (tid & 3) << 2;

    const float* Qp = Q + (size_t)(i0 + lr) * MM + lq;
    const int jrow = j0 + lr;
    const bool jok = (jrow >= 0) && (jrow < NN);
    const float* Kp = Kmat + (size_t)(jok ? jrow : 0) * MM + lq;

    f4v pq = *(const f4v*)(Qp);
    f4v pk = {0.f, 0.f, 0.f, 0.f};
    if (jok) pk = *(const f4v*)(Kp);

    float acc[4][4] = {};

    #pragma unroll
    for (int l = 0; l < 4; ++l) { Qs[0][lq + l][lr] = pq[l]; Ks[0][lq + l][lr] = pk[l]; }
    __syncthreads();

    for (int kt = 0; kt < 64; ++kt) {
        const int cur = kt & 1;
        if (kt + 1 < 64) {
            const int k0 = (kt + 1) << 4;
            pq = *(const f4v*)(Qp + k0);
            if (jok) pk = *(const f4v*)(Kp + k0);
        }
        #pragma unroll
        for (int kk = 0; kk < 16; ++kk) {
            f4v a = *(const f4v*)&Qs[cur][kk][tm << 2];
            f4v b = *(const f4v*)&Ks[cur][kk][tn << 2];
            #pragma unroll
            for (int r = 0; r < 4; ++r) {
                #pragma unroll
                for (int c = 0; c < 4; ++c) acc[r][c] += a[r] * b[c];
            }
        }
        if (kt + 1 < 64) {
            const int nxt = cur ^ 1;
            #pragma unroll
            for (int l = 0; l < 4; ++l) { Qs[nxt][lq + l][lr] = pq[l]; Ks[nxt][lq + l][lr] = pk[l]; }
        }
        __syncthreads();
    }

    #pragma unroll
    for (int r = 0; r < 4; ++r) {
        const int i = i0 + (tm << 2) + r;
        #pragma unroll
        for (int c = 0; c < 4; ++c) {
            const int j = j0 + (tn << 2) + c;
            const int ci = j - i + 255;
            if (ci >= 0 && ci <= 510) {
                const float v = (j >= 0 && j < NN) ? 0.06f * acc[r][c] : -INFINITY;
                band[(size_t)i * BANDP + ci] = v;
            }
        }
    }
}

// ---------------- per-row softmax over the band; writes full att rows -------
__global__ __launch_bounds__(256)
void band_softmax(float* __restrict__ band, float* __restrict__ att)
{
    const int i = blockIdx.x;
    const int tid = threadIdx.x;
    float* brow = band + (size_t)i * BANDP;

    float v0 = brow[tid];
    float v1 = (tid < 255) ? brow[tid + 256] : -INFINITY;

    float m = fmaxf(v0, v1);
    #pragma unroll
    for (int o = 32; o >= 1; o >>= 1) m = fmaxf(m, __shfl_xor(m, o));
    __shared__ float redm[4], reds[4];
    const int wv = tid >> 6, ln = tid & 63;
    if (ln == 0) redm[wv] = m;
    __syncthreads();
    m = fmaxf(fmaxf(redm[0], redm[1]), fmaxf(redm[2], redm[3]));

    float p0 = expf(v0 - m);
    float p1 = (tid < 255) ? expf(v1 - m) : 0.f;
    float s = p0 + p1;
    #pragma unroll
    for (int o = 32; o >= 1; o >>= 1) s += __shfl_xor(s, o);
    if (ln == 0) reds[wv] = s;
    __syncthreads();
    s = reds[0] + reds[1] + reds[2] + reds[3];
    const float rinv = 1.0f / s;
    p0 *= rinv; p1 *= rinv;

    brow[tid] = p0;
    if (tid < 255) brow[tid + 256] = p1;

    float* arow = att + (size_t)i * NN;
    f4v z = {0.f, 0.f, 0.f, 0.f};
    #pragma unroll
    for (int q = 0; q < 4; ++q)
        *(f4v*)&arow[(q * 256 + tid) << 2] = z;
    __syncthreads();
    int j = i + tid - 255;
    if (j >= 0 && j < NN) arow[j] = p0;
    j = i + tid + 1;
    if (tid < 255 && j >= 0 && j < NN) arow[j] = p1;
}

// ---------------- y1 = att.T @ V using the prob band ------------------------
// y1[r][n] = sum_j att[j][r] * V[j][n], j in [r-255, r+255]
__global__ __launch_bounds__(256, 2)
void band_attT_v(const float* __restrict__ band, const float* __restrict__ V,
                 float* __restrict__ y1)
{
    __shared__ float Ws[2][16][68];
    __shared__ float Vs[2][16][128];

    const int tid = threadIdx.x;
    const int r0 = blockIdx.y << 6;
    const int n0 = blockIdx.x << 7;
    const int tm = tid >> 4;
    const int tn = tid & 15;

    const int wjj = tid >> 6;        // 0..3 ; full jj = wjj + 4*l
    const int wrl = tid & 63;
    const int vjj0 = tid >> 5;       // 0..7
    const int vjj1 = vjj0 + 8;       // 8..15
    const int vq  = (tid & 31) << 2;

    float wv[4];
    f4v pv0, pv1;
    const f4v z4 = {0.f, 0.f, 0.f, 0.f};

    auto gload = [&](int jb) {
        #pragma unroll
        for (int l = 0; l < 4; ++l) {
            const int jj = wjj + (l << 2);
            const int j = jb + jj;
            const int c = r0 + wrl - j + 255;
            wv[l] = (j >= 0 && j < NN && c >= 0 && c <= 510)
                  ? band[(size_t)j * BANDP + c] : 0.f;
        }
        int j = jb + vjj0;
        pv0 = (j >= 0 && j < NN) ? *(const f4v*)&V[(size_t)j * MM + n0 + vq] : z4;
        j = jb + vjj1;
        pv1 = (j >= 0 && j < NN) ? *(const f4v*)&V[(size_t)j * MM + n0 + vq] : z4;
    };
    auto sstore = [&](int b) {
        #pragma unroll
        for (int l = 0; l < 4; ++l) Ws[b][wjj + (l << 2)][wrl] = wv[l];
        *(f4v*)&Vs[b][vjj0][vq] = pv0;
        *(f4v*)&Vs[b][vjj1][vq] = pv1;
    };

    float acc[4][2][4] = {};
    const int jb0 = r0 - 255;
    gload(jb0); sstore(0); __syncthreads();

    const int NT = 36;  // 36*16 = 576 >= 64+510
    for (int t = 0; t < NT; ++t) {
        const int cur = t & 1;
        if (t + 1 < NT) gload(jb0 + ((t + 1) << 4));
        #pragma unroll
        for (int kk = 0; kk < 16; ++kk) {
            f4v w  = *(const f4v*)&Ws[cur][kk][tm << 2];
            f4v v0 = *(const f4v*)&Vs[cur][kk][tn << 2];
            f4v v1 = *(const f4v*)&Vs[cur][kk][64 + (tn << 2)];
            #pragma unroll
            for (int r = 0; r < 4; ++r) {
                #pragma unroll
                for (int c = 0; c < 4; ++c) {
                    acc[r][0][c] += w[r] * v0[c];
                    acc[r][1][c] += w[r] * v1[c];
                }
            }
        }
        if (t + 1 < NT) sstore(cur ^ 1);
        __syncthreads();
    }

    #pragma unroll
    for (int r = 0; r < 4; ++r) {
        #pragma unroll
        for (int g = 0; g < 2; ++g) {
            f4v o;
            #pragma unroll
            for (int c = 0; c < 4; ++c) o[c] = acc[r][g][c];
            *(f4v*)&y1[(size_t)(r0 + (tm << 2) + r) * MM + n0 + (g << 6) + (tn << 2)] = o;
        }
    }
}

extern "C" void kernel_launch(void* const* d_in, const int* in_sizes, int n_in,
                              void* d_out, int out_size, void* d_ws, size_t ws_size,
                              hipStream_t stream)
{
    const float* x    = (const float*)d_in[0];
    const float* Wq   = (const float*)d_in[1];
    const float* Wk   = (const float*)d_in[2];
    const float* Wv   = (const float*)d_in[3];
    const float* Wofx = (const float*)d_in[4];
    const float* bofx = (const float*)d_in[5];
    const float* Wofy = (const float*)d_in[6];
    const float* bofy = (const float*)d_in[7];
    const float* Wout = (const float*)d_in[8];

    float* y_out   = (float*)d_out;
    float* att_out = (float*)d_out + (size_t)NN * MM;

    const size_t C4M = (size_t)NN * MM;     // 4M elements
    float* ws   = (float*)d_ws;
    float* Q    = ws;                       // [0, 4M)   Q, later y1
    float* KB   = ws + C4M;                 // [4M, 8M)  ofx, later K
    float* VB   = ws + 2 * C4M;             // [8M,12M)  ofy, later V
    float* XN   = ws + 3 * C4M;             // [12M,16M) x_new, later band (2M)
    float* band = ws + 3 * C4M;             // overlays XN after it is dead
    float* y1   = ws;                       // overlays Q after logits

    const dim3 blk(256);
    const dim3 ggemm(MM / 64, NN / 128);    // (16, 32)

    // Q = x @ Wq
    gemm_f32<<<ggemm, blk, 0, stream>>>(x, Wq, nullptr, Q, NN, MM, MM);
    // ofx = Q @ Wofx + bofx ; ofy = Q @ Wofy + bofy
    gemm_f32<<<ggemm, blk, 0, stream>>>(Q, Wofx, bofx, KB, NN, MM, MM);
    gemm_f32<<<ggemm, blk, 0, stream>>>(Q, Wofy, bofy, VB, NN, MM, MM);
    // x_new = grid_sample(x, ofx, ofy)
    grid_sample_k<<<dim3(NN), blk, 0, stream>>>(x, KB, VB, XN);
    // K = x_new @ Wk ; V = x_new @ Wv   (reuse ofx/ofy buffers)
    gemm_f32<<<ggemm, blk, 0, stream>>>(XN, Wk, nullptr, KB, NN, MM, MM);
    gemm_f32<<<ggemm, blk, 0, stream>>>(XN, Wv, nullptr, VB, NN, MM, MM);
    // banded logits (x_new dead -> band overlays it)
    band_logits<<<dim3(9, NN / 64), blk, 0, stream>>>(Q, KB, band);
    // softmax over band; writes full att rows (incl. zeros) to d_out
    band_softmax<<<dim3(NN), blk, 0, stream>>>(band, att_out);
    // y1 = att.T @ V  (Q dead -> y1 overlays it)
    band_attT_v<<<dim3(MM / 128, NN / 64), blk, 0, stream>>>(band, VB, y1);
    // y = y1 @ Wout -> d_out
    gemm_f32<<<ggemm, blk, 0, stream>>>(y1, Wout, nullptr, y_out, NN, MM, MM);
}

// Round 2
// 608.991 us; speedup vs baseline: 1.6076x; 1.6076x over previous
//
#include <hip/hip_runtime.h>
#include <hip/hip_bf16.h>
#include <math.h>

#define NN 4096
#define MM 1024
#define BANDP 512

typedef float f4v __attribute__((ext_vector_type(4)));
typedef float f32x4 __attribute__((ext_vector_type(4)));
typedef short bf16x8 __attribute__((ext_vector_type(8)));
typedef short s4v __attribute__((ext_vector_type(4)));

__device__ __forceinline__ short f2b(float f) {
    union { float f; unsigned u; } v; v.f = f;
    unsigned r = v.u + 0x7fffu + ((v.u >> 16) & 1u);
    return (short)(r >> 16);
}

__device__ __forceinline__ void gl2lds16(const void* g, void* l) {
    __builtin_amdgcn_global_load_lds(
        (const __attribute__((address_space(1))) void*)g,
        (__attribute__((address_space(3))) void*)l, 16, 0, 0);
}

// ---------------- fp32 GEMM (sensitive path: Q, ofx, ofy) ------------------
__global__ __launch_bounds__(256, 2)
void gemm_f32(const float* __restrict__ A, const float* __restrict__ B,
              const float* __restrict__ bias, float* __restrict__ C,
              int M, int N, int K)
{
    __shared__ float As[2][16][132];
    __shared__ float Bs[2][16][64];

    const int tid = threadIdx.x;
    const int m0 = blockIdx.y << 7;
    const int n0 = blockIdx.x << 6;
    const int tm = tid >> 4;
    const int tn = tid & 15;

    const int ar = tid >> 2;
    const int aq = (tid & 3) << 2;
    const int bk = tid >> 4;
    const int bq = (tid & 15) << 2;

    const float* Ap0 = A + (size_t)(m0 + ar) * K + aq;
    const float* Ap1 = A + (size_t)(m0 + ar + 64) * K + aq;
    const float* Bp  = B + (size_t)bk * N + n0 + bq;

    f4v pa0 = *(const f4v*)(Ap0);
    f4v pa1 = *(const f4v*)(Ap1);
    f4v pb  = *(const f4v*)(Bp);

    float acc0[4][4] = {};
    float acc1[4][4] = {};

    #pragma unroll
    for (int l = 0; l < 4; ++l) {
        As[0][aq + l][ar]      = pa0[l];
        As[0][aq + l][ar + 64] = pa1[l];
    }
    *(f4v*)&Bs[0][bk][bq] = pb;
    __syncthreads();

    const int NKT = K >> 4;
    for (int kt = 0; kt < NKT; ++kt) {
        const int cur = kt & 1;
        if (kt + 1 < NKT) {
            const int k0 = (kt + 1) << 4;
            pa0 = *(const f4v*)(Ap0 + k0);
            pa1 = *(const f4v*)(Ap1 + k0);
            pb  = *(const f4v*)(Bp + (size_t)k0 * N);
        }
        #pragma unroll
        for (int kk = 0; kk < 16; ++kk) {
            f4v a0 = *(const f4v*)&As[cur][kk][tm << 2];
            f4v a1 = *(const f4v*)&As[cur][kk][64 + (tm << 2)];
            f4v b  = *(const f4v*)&Bs[cur][kk][tn << 2];
            #pragma unroll
            for (int r = 0; r < 4; ++r) {
                #pragma unroll
                for (int c = 0; c < 4; ++c) {
                    acc0[r][c] += a0[r] * b[c];
                    acc1[r][c] += a1[r] * b[c];
                }
            }
        }
        if (kt + 1 < NKT) {
            const int nxt = cur ^ 1;
            #pragma unroll
            for (int l = 0; l < 4; ++l) {
                As[nxt][aq + l][ar]      = pa0[l];
                As[nxt][aq + l][ar + 64] = pa1[l];
            }
            *(f4v*)&Bs[nxt][bk][bq] = pb;
        }
        __syncthreads();
    }

    f4v bv = {0.f, 0.f, 0.f, 0.f};
    if (bias) bv = *(const f4v*)&bias[n0 + (tn << 2)];

    #pragma unroll
    for (int r = 0; r < 4; ++r) {
        f4v o0, o1;
        #pragma unroll
        for (int c = 0; c < 4; ++c) { o0[c] = acc0[r][c] + bv[c]; o1[c] = acc1[r][c] + bv[c]; }
        *(f4v*)&C[(size_t)(m0 + (tm << 2) + r) * N + n0 + (tn << 2)]      = o0;
        *(f4v*)&C[(size_t)(m0 + 64 + (tm << 2) + r) * N + n0 + (tn << 2)] = o1;
    }
}

// ---------------- bilinear grid sample -> bf16 ------------------------------
__global__ __launch_bounds__(256)
void grid_sample_k(const float* __restrict__ x, const float* __restrict__ ofx,
                   const float* __restrict__ ofy, short* __restrict__ xnb)
{
    const int i = blockIdx.x;
    const int tid = threadIdx.x;
    const int j4 = tid << 2;

    f4v fx = *(const f4v*)&ofx[(size_t)i * MM + j4];
    f4v fy = *(const f4v*)&ofy[(size_t)i * MM + j4];
    s4v out;

    const float gxb = (2.0f * (float)i) / (float)NN - 1.0f;

    #pragma unroll
    for (int l = 0; l < 4; ++l) {
        const int j = j4 + l;
        float gx = gxb + fx[l];
        gx = fminf(fmaxf(gx, -1.0f), 1.0f);
        float gy = (2.0f * (float)j) / (float)MM - 1.0f + fy[l];
        gy = fminf(fmaxf(gy, -1.0f), 1.0f);

        const float ixf = (gx + 1.0f) * 511.5f;
        const float iyf = (gy + 1.0f) * 2047.5f;
        const float ix0 = floorf(ixf);
        const float iy0 = floorf(iyf);
        const float wx = ixf - ix0;
        const float wy = iyf - iy0;
        int ix0i = (int)ix0; ix0i = max(0, min(ix0i, MM - 1));
        int iy0i = (int)iy0; iy0i = max(0, min(iy0i, NN - 1));
        const int ix1i = min(ix0i + 1, MM - 1);
        const int iy1i = min(iy0i + 1, NN - 1);

        const float* r0 = x + (size_t)iy0i * MM;
        const float* r1 = x + (size_t)iy1i * MM;
        const float v00 = r0[ix0i], v01 = r0[ix1i];
        const float v10 = r1[ix0i], v11 = r1[ix1i];
        out[l] = f2b((1.0f - wy) * ((1.0f - wx) * v00 + wx * v01)
                   + wy * ((1.0f - wx) * v10 + wx * v11));
    }
    *(s4v*)&xnb[(size_t)i * MM + j4] = out;
}

// ---------------- fp32 -> bf16 transpose (weights to B^T layout) ------------
__global__ __launch_bounds__(256)
void transpose_f32_bf16(const float* __restrict__ W, short* __restrict__ Wt)
{
    __shared__ float tile[32][33];
    const int bx = blockIdx.x << 5, by = blockIdx.y << 5;
    const int tx = threadIdx.x, ty = threadIdx.y;
    #pragma unroll
    for (int r = ty; r < 32; r += 8)
        tile[r][tx] = W[(size_t)(by + r) * MM + bx + tx];
    __syncthreads();
    #pragma unroll
    for (int r = ty; r < 32; r += 8)
        Wt[(size_t)(bx + r) * MM + by + tx] = f2b(tile[tx][r]);
}

// ---------------- fp32 -> bf16 elementwise ----------------------------------
__global__ __launch_bounds__(256)
void cvt_f32_bf16(const float* __restrict__ s, short* __restrict__ d)
{
    const int i = (blockIdx.x * 256 + threadIdx.x) << 2;
    f4v v = *(const f4v*)&s[i];
    s4v o;
    #pragma unroll
    for (int l = 0; l < 4; ++l) o[l] = f2b(v[l]);
    *(s4v*)&d[i] = o;
}

// ---------------- MFMA bf16 GEMM, A[4096x1024] @ Bt[.][1024]^T --------------
// MODE 0: C bf16 row-major [4096][1024]
// MODE 1: C bf16 transposed [1024][4096]   (Vt)
// MODE 2: C fp32 row-major [4096][1024]
// MODE 3: banded logits -> band fp32 [4096][512] with -inf mask; Bt=K[4096][1024]
template<int MODE>
__global__ __launch_bounds__(256, 2)
void mfma_gemm(const short* __restrict__ A, const short* __restrict__ Bt,
               void* __restrict__ Cout)
{
    __shared__ short As[2][128 * 32];
    __shared__ short Bs[2][128 * 32];

    const int t  = threadIdx.x;
    const int l  = t & 63;
    const int w  = t >> 6;
    const int wm = w >> 1, wn = w & 1;
    const int lr = l & 15;
    const int lk = (l >> 4) << 3;

    const int i0 = blockIdx.y << 7;
    const int bn = blockIdx.x << 7;
    const int jb = (MODE == 3) ? (i0 - 256 + bn) : bn;

    const int sr = t >> 2;
    const int sk = (t & 3) << 3;

    const short* aS = A + (size_t)(i0 + sr) * MM + sk;
    int br0 = jb + sr, br1 = jb + sr + 64;
    if (MODE == 3) {
        br0 = min(max(br0, 0), NN - 1);
        br1 = min(max(br1, 0), NN - 1);
    }
    const short* bS0 = Bt + (size_t)br0 * MM + sk;
    const short* bS1 = Bt + (size_t)br1 * MM + sk;

    f32x4 acc[4][4] = {};

    auto stage = [&](int sb, int k0) {
        gl2lds16(aS + k0,           &As[sb][0] + t * 8);
        gl2lds16(aS + 64 * MM + k0, &As[sb][0] + 2048 + t * 8);
        gl2lds16(bS0 + k0,          &Bs[sb][0] + t * 8);
        gl2lds16(bS1 + k0,          &Bs[sb][0] + 2048 + t * 8);
    };
    stage(0, 0);
    __syncthreads();

    for (int kt = 0; kt < 32; ++kt) {
        const int cur = kt & 1;
        if (kt + 1 < 32) stage(cur ^ 1, (kt + 1) << 5);
        bf16x8 a[4], b[4];
        #pragma unroll
        for (int i = 0; i < 4; ++i)
            a[i] = *(const bf16x8*)&As[cur][(wm * 64 + i * 16 + lr) * 32 + lk];
        #pragma unroll
        for (int j = 0; j < 4; ++j)
            b[j] = *(const bf16x8*)&Bs[cur][(wn * 64 + j * 16 + lr) * 32 + lk];
        #pragma unroll
        for (int i = 0; i < 4; ++i)
            #pragma unroll
            for (int j = 0; j < 4; ++j)
                acc[i][j] = __builtin_amdgcn_mfma_f32_16x16x32_bf16(a[i], b[j], acc[i][j], 0, 0, 0);
        __syncthreads();
    }

    const int rb = (l >> 4) << 2;
    #pragma unroll
    for (int i = 0; i < 4; ++i) {
        #pragma unroll
        for (int j = 0; j < 4; ++j) {
            const int nl = wn * 64 + j * 16 + lr;
            if (MODE == 1) {
                const int m0 = i0 + wm * 64 + i * 16 + rb;
                s4v o;
                #pragma unroll
                for (int r = 0; r < 4; ++r) o[r] = f2b(acc[i][j][r]);
                *(s4v*)&((short*)Cout)[(size_t)(bn + nl) * NN + m0] = o;
            } else {
                #pragma unroll
                for (int r = 0; r < 4; ++r) {
                    const int m = i0 + wm * 64 + i * 16 + rb + r;
                    const float v = acc[i][j][r];
                    if (MODE == 0) {
                        ((short*)Cout)[(size_t)m * MM + bn + nl] = f2b(v);
                    } else if (MODE == 2) {
                        ((float*)Cout)[(size_t)m * MM + bn + nl] = v;
                    } else if (MODE == 3) {
                        const int jj = jb + nl;
                        const int ci = jj - m + 255;
                        if (ci >= 0 && ci <= 510)
                            ((float*)Cout)[(size_t)m * BANDP + ci] =
                                (jj >= 0 && jj < NN) ? 0.06f * v : -INFINITY;
                    }
                }
            }
        }
    }
}

// ---------------- softmax over band; writes att rows + bandT scatter --------
__global__ __launch_bounds__(256)
void band_softmax(const float* __restrict__ band, float* __restrict__ att,
                  short* __restrict__ bandT)
{
    const int i = blockIdx.x;
    const int tid = threadIdx.x;
    const float* brow = band + (size_t)i * BANDP;

    float v0 = brow[tid];
    float v1 = (tid < 255) ? brow[tid + 256] : -INFINITY;

    float m = fmaxf(v0, v1);
    #pragma unroll
    for (int o = 32; o >= 1; o >>= 1) m = fmaxf(m, __shfl_xor(m, o));
    __shared__ float redm[4], reds[4];
    const int wv = tid >> 6, ln = tid & 63;
    if (ln == 0) redm[wv] = m;
    __syncthreads();
    m = fmaxf(fmaxf(redm[0], redm[1]), fmaxf(redm[2], redm[3]));

    float p0 = expf(v0 - m);
    float p1 = (tid < 255) ? expf(v1 - m) : 0.f;
    float s = p0 + p1;
    #pragma unroll
    for (int o = 32; o >= 1; o >>= 1) s += __shfl_xor(s, o);
    if (ln == 0) reds[wv] = s;
    __syncthreads();
    s = reds[0] + reds[1] + reds[2] + reds[3];
    const float rinv = 1.0f / s;
    p0 *= rinv; p1 *= rinv;

    float* arow = att + (size_t)i * NN;
    f4v z = {0.f, 0.f, 0.f, 0.f};
    #pragma unroll
    for (int q = 0; q < 4; ++q)
        *(f4v*)&arow[(q * 256 + tid) << 2] = z;
    __syncthreads();
    int j = i + tid - 255;
    if (j >= 0 && j < NN) {
        arow[j] = p0;
        bandT[(size_t)j * 768 + (i - (j & ~7) + 384)] = f2b(p0);
    }
    j = i + tid + 1;
    if (tid < 255 && j >= 0 && j < NN) {
        arow[j] = p1;
        bandT[(size_t)j * 768 + (i - (j & ~7) + 384)] = f2b(p1);
    }
}

// ---------------- y1 = att^T @ V via MFMA, direct-global operands -----------
__global__ __launch_bounds__(256, 2)
void attT_v_mfma(const short* __restrict__ bandT, const short* __restrict__ Vt,
                 short* __restrict__ y1b)
{
    const int t = threadIdx.x, l = t & 63, w = t >> 6;
    const int wm = w >> 1, wn = w & 1;
    const int lr = l & 15, lk = (l >> 4) << 3;
    const int r0 = blockIdx.y << 7;
    const int n0 = blockIdx.x << 6;

    f32x4 acc[4][2] = {};
    for (int ks = 0; ks < 20; ++ks) {
        const int j0 = r0 - 256 + (ks << 5);
        if (j0 < 0 || j0 >= NN) continue;
        bf16x8 b[2];
        #pragma unroll
        for (int j = 0; j < 2; ++j)
            b[j] = *(const bf16x8*)&Vt[(size_t)(n0 + wn * 32 + j * 16 + lr) * NN + j0 + lk];
        #pragma unroll
        for (int i = 0; i < 4; ++i) {
            const int r = r0 + wm * 64 + i * 16 + lr;
            const int cc = j0 + lk - (r & ~7) + 384;
            bf16x8 a = *(const bf16x8*)&bandT[(size_t)r * 768 + cc];
            #pragma unroll
            for (int j = 0; j < 2; ++j)
                acc[i][j] = __builtin_amdgcn_mfma_f32_16x16x32_bf16(a, b[j], acc[i][j], 0, 0, 0);
        }
    }
    const int rb = (l >> 4) << 2;
    #pragma unroll
    for (int i = 0; i < 4; ++i)
        #pragma unroll
        for (int j = 0; j < 2; ++j)
            #pragma unroll
            for (int r = 0; r < 4; ++r)
                y1b[(size_t)(r0 + wm * 64 + i * 16 + rb + r) * MM + n0 + wn * 32 + j * 16 + lr]
                    = f2b(acc[i][j][r]);
}

extern "C" void kernel_launch(void* const* d_in, const int* in_sizes, int n_in,
                              void* d_out, int out_size, void* d_ws, size_t ws_size,
                              hipStream_t stream)
{
    const float* x    = (const float*)d_in[0];
    const float* Wq   = (const float*)d_in[1];
    const float* Wk   = (const float*)d_in[2];
    const float* Wv   = (const float*)d_in[3];
    const float* Wofx = (const float*)d_in[4];
    const float* bofx = (const float*)d_in[5];
    const float* Wofy = (const float*)d_in[6];
    const float* bofy = (const float*)d_in[7];
    const float* Wout = (const float*)d_in[8];

    float* y_out   = (float*)d_out;
    float* att_out = (float*)d_out + (size_t)NN * MM;

    char* wsb = (char*)d_ws;
    const size_t MB = 1024 * 1024;
    float* Q     = (float*)(wsb + 0);        // [0,16) MB fp32
    float* ofx   = (float*)(wsb + 16 * MB);  // [16,32) fp32
    float* ofy   = (float*)(wsb + 32 * MB);  // [32,48) fp32
    // overlays (after grid_sample frees ofx/ofy):
    short* WkT   = (short*)(wsb + 16 * MB);  // [16,18) bf16
    short* WvT   = (short*)(wsb + 18 * MB);  // [18,20) bf16
    float* band  = (float*)(wsb + 16 * MB);  // [16,24) fp32 (after WkT/WvT dead)
    short* bandT = (short*)(wsb + 24 * MB);  // [24,30) bf16 4096x768
    short* WoutT = (short*)(wsb + 30 * MB);  // [30,32) bf16
    short* Kb    = (short*)(wsb + 32 * MB);  // [32,40) bf16
    short* y1b   = (short*)(wsb + 40 * MB);  // [40,48) bf16
    short* xnb   = (short*)(wsb + 48 * MB);  // [48,56) bf16 (Qb overlays later)
    short* Qb    = (short*)(wsb + 48 * MB);
    short* Vtb   = (short*)(wsb + 56 * MB);  // [56,64) bf16 [1024][4096]

    const dim3 blk(256);
    const dim3 ggemm(MM / 64, NN / 128);

    // fp32 sensitive path
    gemm_f32<<<ggemm, blk, 0, stream>>>(x, Wq, nullptr, Q, NN, MM, MM);
    gemm_f32<<<ggemm, blk, 0, stream>>>(Q, Wofx, bofx, ofx, NN, MM, MM);
    gemm_f32<<<ggemm, blk, 0, stream>>>(Q, Wofy, bofy, ofy, NN, MM, MM);
    grid_sample_k<<<dim3(NN), blk, 0, stream>>>(x, ofx, ofy, xnb);

    // weights -> bf16 B^T layout (ofx/ofy slots now free)
    transpose_f32_bf16<<<dim3(32, 32), dim3(32, 8), 0, stream>>>(Wk, WkT);
    transpose_f32_bf16<<<dim3(32, 32), dim3(32, 8), 0, stream>>>(Wv, WvT);
    transpose_f32_bf16<<<dim3(32, 32), dim3(32, 8), 0, stream>>>(Wout, WoutT);

    // K = xn @ Wk (bf16), Vt = (xn @ Wv)^T (bf16)
    mfma_gemm<0><<<dim3(8, 32), blk, 0, stream>>>(xnb, WkT, Kb);
    mfma_gemm<1><<<dim3(8, 32), blk, 0, stream>>>(xnb, WvT, Vtb);

    // Qb (xnb slot now free)
    cvt_f32_bf16<<<dim3(4096), blk, 0, stream>>>(Q, Qb);

    // banded logits (WkT/WvT dead -> band overlays)
    mfma_gemm<3><<<dim3(5, 32), blk, 0, stream>>>(Qb, Kb, band);

    // softmax -> att rows in d_out + bandT bf16 scatter
    hipMemsetAsync(bandT, 0, (size_t)NN * 768 * sizeof(short), stream);
    band_softmax<<<dim3(NN), blk, 0, stream>>>(band, att_out, bandT);

    // y1 = att^T @ V (bf16)
    attT_v_mfma<<<dim3(16, 32), blk, 0, stream>>>(bandT, Vtb, y1b);

    // y = y1 @ Wout -> fp32 d_out
    mfma_gemm<2><<<dim3(8, 32), blk, 0, stream>>>(y1b, WoutT, y_out);
}

// Round 4
// 351.524 us; speedup vs baseline: 2.7850x; 1.7324x over previous
//
#include <hip/hip_runtime.h>
#include <hip/hip_bf16.h>
#include <math.h>

#define NN 4096
#define MM 1024
#define BANDP 512

typedef float f4v __attribute__((ext_vector_type(4)));
typedef float f32x4 __attribute__((ext_vector_type(4)));
typedef short bf16x8 __attribute__((ext_vector_type(8)));
typedef short s4v __attribute__((ext_vector_type(4)));

__device__ __forceinline__ short f2b(float f) {
    union { float f; unsigned u; } v; v.f = f;
    unsigned r = v.u + 0x7fffu + ((v.u >> 16) & 1u);
    return (short)(r >> 16);
}
__device__ __forceinline__ float b2f(short s) {
    union { unsigned u; float f; } v;
    v.u = ((unsigned)(unsigned short)s) << 16;
    return v.f;
}

__device__ __forceinline__ void gl2lds16(const void* g, void* l) {
    __builtin_amdgcn_global_load_lds(
        (const __attribute__((address_space(1))) void*)g,
        (__attribute__((address_space(3))) void*)l, 16, 0, 0);
}

// ---------------- x (fp32) -> bf16 hi/lo split ------------------------------
__global__ __launch_bounds__(256)
void split_x_k(const float* __restrict__ s, short* __restrict__ h,
               short* __restrict__ l)
{
    const int i = (blockIdx.x * 256 + threadIdx.x) << 2;
    f4v v = *(const f4v*)&s[i];
    s4v hv, lv;
    #pragma unroll
    for (int q = 0; q < 4; ++q) {
        hv[q] = f2b(v[q]);
        lv[q] = f2b(v[q] - b2f(hv[q]));
    }
    *(s4v*)&h[i] = hv;
    *(s4v*)&l[i] = lv;
}

// ---------------- fp32 weight -> transposed bf16 hi/lo ----------------------
__global__ __launch_bounds__(256)
void trsplit_k(const float* __restrict__ W, short* __restrict__ Th,
               short* __restrict__ Tl)
{
    __shared__ float tile[32][33];
    const int bx = blockIdx.x << 5, by = blockIdx.y << 5;
    const int tx = threadIdx.x, ty = threadIdx.y;
    #pragma unroll
    for (int r = ty; r < 32; r += 8)
        tile[r][tx] = W[(size_t)(by + r) * MM + bx + tx];
    __syncthreads();
    #pragma unroll
    for (int r = ty; r < 32; r += 8) {
        const float v = tile[tx][r];
        const short h = f2b(v);
        Th[(size_t)(bx + r) * MM + by + tx] = h;
        Tl[(size_t)(bx + r) * MM + by + tx] = f2b(v - b2f(h));
    }
}

// ---------------- fp32 weight -> transposed bf16 (single) -------------------
__global__ __launch_bounds__(256)
void transpose_f32_bf16(const float* __restrict__ W, short* __restrict__ Wt)
{
    __shared__ float tile[32][33];
    const int bx = blockIdx.x << 5, by = blockIdx.y << 5;
    const int tx = threadIdx.x, ty = threadIdx.y;
    #pragma unroll
    for (int r = ty; r < 32; r += 8)
        tile[r][tx] = W[(size_t)(by + r) * MM + bx + tx];
    __syncthreads();
    #pragma unroll
    for (int r = ty; r < 32; r += 8)
        Wt[(size_t)(bx + r) * MM + by + tx] = f2b(tile[tx][r]);
}

// ---------------- split-bf16 3-term MFMA GEMM (fp32-faithful path) ----------
// C = (Ah+Al)[MxK] @ (Bh+Bl)^T[NxK], dropping Al*Bl. Out: bf16 hi/lo pair.
template<bool BIAS>
__global__ __launch_bounds__(256, 2)
void gemm_split(const short* __restrict__ Ah, const short* __restrict__ Al,
                const short* __restrict__ Bth, const short* __restrict__ Btl,
                const float* __restrict__ bias0, const float* __restrict__ bias1,
                short* __restrict__ outH, short* __restrict__ outL, int N)
{
    __shared__ short As[2][2][128 * 32];
    __shared__ short Bs[2][2][128 * 32];

    const int t  = threadIdx.x;
    const int l  = t & 63;
    const int w  = t >> 6;
    const int wm = w >> 1, wn = w & 1;
    const int lr = l & 15;
    const int lk = (l >> 4) << 3;

    const int i0 = blockIdx.y << 7;
    const int bn = blockIdx.x << 7;

    const int sr = t >> 2;
    const int sk = (t & 3) << 3;

    const short* aH = Ah  + (size_t)(i0 + sr) * MM + sk;
    const short* aL = Al  + (size_t)(i0 + sr) * MM + sk;
    const short* bH = Bth + (size_t)(bn + sr) * MM + sk;
    const short* bL = Btl + (size_t)(bn + sr) * MM + sk;

    f32x4 acc[4][4] = {};

    auto stage = [&](int sb, int k0) {
        gl2lds16(aH + k0,           &As[sb][0][t * 8]);
        gl2lds16(aH + 64 * MM + k0, &As[sb][0][2048 + t * 8]);
        gl2lds16(aL + k0,           &As[sb][1][t * 8]);
        gl2lds16(aL + 64 * MM + k0, &As[sb][1][2048 + t * 8]);
        gl2lds16(bH + k0,           &Bs[sb][0][t * 8]);
        gl2lds16(bH + 64 * MM + k0, &Bs[sb][0][2048 + t * 8]);
        gl2lds16(bL + k0,           &Bs[sb][1][t * 8]);
        gl2lds16(bL + 64 * MM + k0, &Bs[sb][1][2048 + t * 8]);
    };
    stage(0, 0);
    __syncthreads();

    for (int kt = 0; kt < 32; ++kt) {
        const int cur = kt & 1;
        if (kt + 1 < 32) stage(cur ^ 1, (kt + 1) << 5);
        bf16x8 ah[4], al[4], bh[4], bl[4];
        #pragma unroll
        for (int i = 0; i < 4; ++i) {
            ah[i] = *(const bf16x8*)&As[cur][0][(wm * 64 + i * 16 + lr) * 32 + lk];
            al[i] = *(const bf16x8*)&As[cur][1][(wm * 64 + i * 16 + lr) * 32 + lk];
        }
        #pragma unroll
        for (int j = 0; j < 4; ++j) {
            bh[j] = *(const bf16x8*)&Bs[cur][0][(wn * 64 + j * 16 + lr) * 32 + lk];
            bl[j] = *(const bf16x8*)&Bs[cur][1][(wn * 64 + j * 16 + lr) * 32 + lk];
        }
        #pragma unroll
        for (int i = 0; i < 4; ++i)
            #pragma unroll
            for (int j = 0; j < 4; ++j) {
                acc[i][j] = __builtin_amdgcn_mfma_f32_16x16x32_bf16(ah[i], bl[j], acc[i][j], 0, 0, 0);
                acc[i][j] = __builtin_amdgcn_mfma_f32_16x16x32_bf16(al[i], bh[j], acc[i][j], 0, 0, 0);
                acc[i][j] = __builtin_amdgcn_mfma_f32_16x16x32_bf16(ah[i], bh[j], acc[i][j], 0, 0, 0);
            }
        __syncthreads();
    }

    const int rb = (l >> 4) << 2;
    #pragma unroll
    for (int i = 0; i < 4; ++i)
        #pragma unroll
        for (int j = 0; j < 4; ++j) {
            const int n = bn + wn * 64 + j * 16 + lr;
            float bv = 0.f;
            if (BIAS) bv = (n < 1024) ? bias0[n] : bias1[n - 1024];
            #pragma unroll
            for (int r = 0; r < 4; ++r) {
                const int m = i0 + wm * 64 + i * 16 + rb + r;
                const float v = acc[i][j][r] + bv;
                const short h = f2b(v);
                outH[(size_t)m * N + n] = h;
                outL[(size_t)m * N + n] = f2b(v - b2f(h));
            }
        }
}

// ---------------- bilinear grid sample (hi/lo coords) -> bf16 ---------------
__global__ __launch_bounds__(256)
void grid_sample_k(const float* __restrict__ x, const short* __restrict__ ofh,
                   const short* __restrict__ ofl, short* __restrict__ xnb)
{
    const int i = blockIdx.x;
    const int tid = threadIdx.x;
    const int j4 = tid << 2;

    const short* rh = ofh + (size_t)i * 2048;
    const short* rl = ofl + (size_t)i * 2048;
    s4v hx = *(const s4v*)&rh[j4];
    s4v lx = *(const s4v*)&rl[j4];
    s4v hy = *(const s4v*)&rh[1024 + j4];
    s4v ly = *(const s4v*)&rl[1024 + j4];
    s4v out;

    const float gxb = (2.0f * (float)i) / (float)NN - 1.0f;

    #pragma unroll
    for (int q = 0; q < 4; ++q) {
        const int j = j4 + q;
        float gx = gxb + b2f(hx[q]) + b2f(lx[q]);
        gx = fminf(fmaxf(gx, -1.0f), 1.0f);
        float gy = (2.0f * (float)j) / (float)MM - 1.0f + b2f(hy[q]) + b2f(ly[q]);
        gy = fminf(fmaxf(gy, -1.0f), 1.0f);

        const float ixf = (gx + 1.0f) * 511.5f;
        const float iyf = (gy + 1.0f) * 2047.5f;
        const float ix0 = floorf(ixf);
        const float iy0 = floorf(iyf);
        const float wx = ixf - ix0;
        const float wy = iyf - iy0;
        int ix0i = (int)ix0; ix0i = max(0, min(ix0i, MM - 1));
        int iy0i = (int)iy0; iy0i = max(0, min(iy0i, NN - 1));
        const int ix1i = min(ix0i + 1, MM - 1);
        const int iy1i = min(iy0i + 1, NN - 1);

        const float* r0 = x + (size_t)iy0i * MM;
        const float* r1 = x + (size_t)iy1i * MM;
        const float v00 = r0[ix0i], v01 = r0[ix1i];
        const float v10 = r1[ix0i], v11 = r1[ix1i];
        out[q] = f2b((1.0f - wy) * ((1.0f - wx) * v00 + wx * v01)
                   + wy * ((1.0f - wx) * v10 + wx * v11));
    }
    *(s4v*)&xnb[(size_t)i * MM + j4] = out;
}

// ---------------- bf16 MFMA GEMM, A[4096x1024] @ Bt^T -----------------------
// MODE 2: C0 fp32 row-major [4096][1024]
// MODE 3: banded logits -> C0 band fp32 [4096][512] with -inf mask; Bt=K
// MODE 4: fused K|V: n<1024 -> C0 = K bf16 [4096][1024]; else C1 = Vt bf16 [1024][4096]
template<int MODE>
__global__ __launch_bounds__(256, 2)
void mfma_gemm(const short* __restrict__ A, const short* __restrict__ Bt,
               void* __restrict__ C0, void* __restrict__ C1)
{
    __shared__ short As[2][128 * 32];
    __shared__ short Bs[2][128 * 32];

    const int t  = threadIdx.x;
    const int l  = t & 63;
    const int w  = t >> 6;
    const int wm = w >> 1, wn = w & 1;
    const int lr = l & 15;
    const int lk = (l >> 4) << 3;

    const int i0 = blockIdx.y << 7;
    const int bn = blockIdx.x << 7;
    const int jb = (MODE == 3) ? (i0 - 256 + bn) : bn;

    const int sr = t >> 2;
    const int sk = (t & 3) << 3;

    const short* aS = A + (size_t)(i0 + sr) * MM + sk;
    int br0 = jb + sr, br1 = jb + sr + 64;
    if (MODE == 3) {
        br0 = min(max(br0, 0), NN - 1);
        br1 = min(max(br1, 0), NN - 1);
    }
    const short* bS0 = Bt + (size_t)br0 * MM + sk;
    const short* bS1 = Bt + (size_t)br1 * MM + sk;

    f32x4 acc[4][4] = {};

    auto stage = [&](int sb, int k0) {
        gl2lds16(aS + k0,           &As[sb][0] + t * 8);
        gl2lds16(aS + 64 * MM + k0, &As[sb][0] + 2048 + t * 8);
        gl2lds16(bS0 + k0,          &Bs[sb][0] + t * 8);
        gl2lds16(bS1 + k0,          &Bs[sb][0] + 2048 + t * 8);
    };
    stage(0, 0);
    __syncthreads();

    for (int kt = 0; kt < 32; ++kt) {
        const int cur = kt & 1;
        if (kt + 1 < 32) stage(cur ^ 1, (kt + 1) << 5);
        bf16x8 a[4], b[4];
        #pragma unroll
        for (int i = 0; i < 4; ++i)
            a[i] = *(const bf16x8*)&As[cur][(wm * 64 + i * 16 + lr) * 32 + lk];
        #pragma unroll
        for (int j = 0; j < 4; ++j)
            b[j] = *(const bf16x8*)&Bs[cur][(wn * 64 + j * 16 + lr) * 32 + lk];
        #pragma unroll
        for (int i = 0; i < 4; ++i)
            #pragma unroll
            for (int j = 0; j < 4; ++j)
                acc[i][j] = __builtin_amdgcn_mfma_f32_16x16x32_bf16(a[i], b[j], acc[i][j], 0, 0, 0);
        __syncthreads();
    }

    const int rb = (l >> 4) << 2;
    #pragma unroll
    for (int i = 0; i < 4; ++i) {
        #pragma unroll
        for (int j = 0; j < 4; ++j) {
            const int nl = wn * 64 + j * 16 + lr;
            if (MODE == 4 && bn + nl >= 1024) {
                const int m0 = i0 + wm * 64 + i * 16 + rb;
                s4v o;
                #pragma unroll
                for (int r = 0; r < 4; ++r) o[r] = f2b(acc[i][j][r]);
                *(s4v*)&((short*)C1)[(size_t)(bn + nl - 1024) * NN + m0] = o;
            } else {
                #pragma unroll
                for (int r = 0; r < 4; ++r) {
                    const int m = i0 + wm * 64 + i * 16 + rb + r;
                    const float v = acc[i][j][r];
                    if (MODE == 4) {
                        ((short*)C0)[(size_t)m * MM + bn + nl] = f2b(v);
                    } else if (MODE == 2) {
                        ((float*)C0)[(size_t)m * MM + bn + nl] = v;
                    } else if (MODE == 3) {
                        const int jj = jb + nl;
                        const int ci = jj - m + 255;
                        if (ci >= 0 && ci <= 510)
                            ((float*)C0)[(size_t)m * BANDP + ci] =
                                (jj >= 0 && jj < NN) ? 0.06f * v : -INFINITY;
                    }
                }
            }
        }
    }
}

// ---------------- softmax over band; writes att rows + bandT scatter --------
__global__ __launch_bounds__(256)
void band_softmax(const float* __restrict__ band, float* __restrict__ att,
                  short* __restrict__ bandT)
{
    const int i = blockIdx.x;
    const int tid = threadIdx.x;
    const float* brow = band + (size_t)i * BANDP;

    float v0 = brow[tid];
    float v1 = (tid < 255) ? brow[tid + 256] : -INFINITY;

    float m = fmaxf(v0, v1);
    #pragma unroll
    for (int o = 32; o >= 1; o >>= 1) m = fmaxf(m, __shfl_xor(m, o));
    __shared__ float redm[4], reds[4];
    const int wv = tid >> 6, ln = tid & 63;
    if (ln == 0) redm[wv] = m;
    __syncthreads();
    m = fmaxf(fmaxf(redm[0], redm[1]), fmaxf(redm[2], redm[3]));

    float p0 = expf(v0 - m);
    float p1 = (tid < 255) ? expf(v1 - m) : 0.f;
    float s = p0 + p1;
    #pragma unroll
    for (int o = 32; o >= 1; o >>= 1) s += __shfl_xor(s, o);
    if (ln == 0) reds[wv] = s;
    __syncthreads();
    s = reds[0] + reds[1] + reds[2] + reds[3];
    const float rinv = 1.0f / s;
    p0 *= rinv; p1 *= rinv;

    float* arow = att + (size_t)i * NN;
    f4v z = {0.f, 0.f, 0.f, 0.f};
    #pragma unroll
    for (int q = 0; q < 4; ++q)
        *(f4v*)&arow[(q * 256 + tid) << 2] = z;
    __syncthreads();
    int j = i + tid - 255;
    if (j >= 0 && j < NN) {
        arow[j] = p0;
        bandT[(size_t)j * 768 + (i - (j & ~7) + 384)] = f2b(p0);
    }
    j = i + tid + 1;
    if (tid < 255 && j >= 0 && j < NN) {
        arow[j] = p1;
        bandT[(size_t)j * 768 + (i - (j & ~7) + 384)] = f2b(p1);
    }
}

// ---------------- y1 = att^T @ V via MFMA, direct-global operands -----------
__global__ __launch_bounds__(256, 2)
void attT_v_mfma(const short* __restrict__ bandT, const short* __restrict__ Vt,
                 short* __restrict__ y1b)
{
    const int t = threadIdx.x, l = t & 63, w = t >> 6;
    const int wm = w >> 1, wn = w & 1;
    const int lr = l & 15, lk = (l >> 4) << 3;
    const int r0 = blockIdx.y << 7;
    const int n0 = blockIdx.x << 6;

    f32x4 acc[4][2] = {};
    for (int ks = 0; ks < 20; ++ks) {
        const int j0 = r0 - 256 + (ks << 5);
        if (j0 < 0 || j0 >= NN) continue;
        bf16x8 b[2];
        #pragma unroll
        for (int j = 0; j < 2; ++j)
            b[j] = *(const bf16x8*)&Vt[(size_t)(n0 + wn * 32 + j * 16 + lr) * NN + j0 + lk];
        #pragma unroll
        for (int i = 0; i < 4; ++i) {
            const int r = r0 + wm * 64 + i * 16 + lr;
            const int cc = j0 + lk - (r & ~7) + 384;
            bf16x8 a = *(const bf16x8*)&bandT[(size_t)r * 768 + cc];
            #pragma unroll
            for (int j = 0; j < 2; ++j)
                acc[i][j] = __builtin_amdgcn_mfma_f32_16x16x32_bf16(a, b[j], acc[i][j], 0, 0, 0);
        }
    }
    const int rb = (l >> 4) << 2;
    #pragma unroll
    for (int i = 0; i < 4; ++i)
        #pragma unroll
        for (int j = 0; j < 2; ++j)
            #pragma unroll
            for (int r = 0; r < 4; ++r)
                y1b[(size_t)(r0 + wm * 64 + i * 16 + rb + r) * MM + n0 + wn * 32 + j * 16 + lr]
                    = f2b(acc[i][j][r]);
}

extern "C" void kernel_launch(void* const* d_in, const int* in_sizes, int n_in,
                              void* d_out, int out_size, void* d_ws, size_t ws_size,
                              hipStream_t stream)
{
    const float* x    = (const float*)d_in[0];
    const float* Wq   = (const float*)d_in[1];
    const float* Wk   = (const float*)d_in[2];
    const float* Wv   = (const float*)d_in[3];
    const float* Wofx = (const float*)d_in[4];
    const float* bofx = (const float*)d_in[5];
    const float* Wofy = (const float*)d_in[6];
    const float* bofy = (const float*)d_in[7];
    const float* Wout = (const float*)d_in[8];

    float* y_out   = (float*)d_out;
    float* att_out = (float*)d_out + (size_t)NN * MM;

    char* wsb = (char*)d_ws;
    const size_t MB = 1024 * 1024;
    // Liveness-verified layout (MB ranges), peak 56 MB:
    //  step                    live buffers
    //  Q-GEMM      reads xh[16,24) xl[24,32) WqT[32,36) -> Qh[0,8) Ql[8,16)
    //  ofxy-GEMM   reads Qh Ql WofxyT[16,24) -> ofxyh[24,40) ofxyl[40,56)
    //  grid_sample reads ofxy* -> xnb[8,16)           (Ql dead)
    //  KV-GEMM     reads xnb WkvT[16,20) -> Kb[24,32) Vtb[32,40)
    //  logits      reads Qh Kb -> band[40,48)
    //  softmax     reads band -> att_out, bandT[0,6)  (Qh dead, stream-ordered)
    //  attT_v      reads bandT Vtb -> y1b[8,16)
    //  final       reads y1b WoutT[20,22) -> y_out
    short* Qh      = (short*)(wsb + 0);
    short* Ql      = (short*)(wsb + 8 * MB);
    short* xh      = (short*)(wsb + 16 * MB);
    short* xl      = (short*)(wsb + 24 * MB);
    short* WqTh    = (short*)(wsb + 32 * MB);
    short* WqTl    = (short*)(wsb + 34 * MB);
    short* WofxyTh = (short*)(wsb + 16 * MB);   // over xh (dead)
    short* WofxyTl = (short*)(wsb + 20 * MB);
    short* ofxyh   = (short*)(wsb + 24 * MB);   // over xl/WqT (dead)
    short* ofxyl   = (short*)(wsb + 40 * MB);
    short* xnb     = (short*)(wsb + 8 * MB);    // over Ql (dead)
    short* WkvT    = (short*)(wsb + 16 * MB);   // over WofxyT (dead)
    short* WoutT   = (short*)(wsb + 20 * MB);
    short* Kb      = (short*)(wsb + 24 * MB);   // over ofxyh (dead)
    short* Vtb     = (short*)(wsb + 32 * MB);
    float* band    = (float*)(wsb + 40 * MB);   // over ofxyl (dead)
    short* bandT   = (short*)(wsb + 0);         // over Qh (dead after logits)
    short* y1b     = (short*)(wsb + 8 * MB);    // over xnb (dead)

    const dim3 blk(256);
    const dim3 tgrid(32, 32), tblk(32, 8);

    // ---- sensitive path via split-bf16 MFMA ----
    split_x_k<<<dim3(4096), blk, 0, stream>>>(x, xh, xl);
    trsplit_k<<<tgrid, tblk, 0, stream>>>(Wq, WqTh, WqTl);
    gemm_split<false><<<dim3(8, 32), blk, 0, stream>>>(
        xh, xl, WqTh, WqTl, nullptr, nullptr, Qh, Ql, 1024);
    trsplit_k<<<tgrid, tblk, 0, stream>>>(Wofx, WofxyTh, WofxyTl);
    trsplit_k<<<tgrid, tblk, 0, stream>>>(Wofy, WofxyTh + 1024 * 1024, WofxyTl + 1024 * 1024);
    gemm_split<true><<<dim3(16, 32), blk, 0, stream>>>(
        Qh, Ql, WofxyTh, WofxyTl, bofx, bofy, ofxyh, ofxyl, 2048);

    grid_sample_k<<<dim3(NN), blk, 0, stream>>>(x, ofxyh, ofxyl, xnb);

    // ---- bf16 path ----
    transpose_f32_bf16<<<tgrid, tblk, 0, stream>>>(Wk, WkvT);
    transpose_f32_bf16<<<tgrid, tblk, 0, stream>>>(Wv, WkvT + 1024 * 1024);
    transpose_f32_bf16<<<tgrid, tblk, 0, stream>>>(Wout, WoutT);

    // K | Vt fused
    mfma_gemm<4><<<dim3(16, 32), blk, 0, stream>>>(xnb, WkvT, Kb, Vtb);
    // banded logits
    mfma_gemm<3><<<dim3(5, 32), blk, 0, stream>>>(Qh, Kb, band, nullptr);
    // softmax -> att rows in d_out + bandT bf16 scatter
    hipMemsetAsync(bandT, 0, (size_t)NN * 768 * sizeof(short), stream);
    band_softmax<<<dim3(NN), blk, 0, stream>>>(band, att_out, bandT);
    // y1 = att^T @ V
    attT_v_mfma<<<dim3(16, 32), blk, 0, stream>>>(bandT, Vtb, y1b);
    // y = y1 @ Wout
    mfma_gemm<2><<<dim3(8, 32), blk, 0, stream>>>(y1b, WoutT, y_out, nullptr);
}

// Round 5
// 334.453 us; speedup vs baseline: 2.9271x; 1.0510x over previous
//
#include <hip/hip_runtime.h>
#include <hip/hip_bf16.h>
#include <math.h>

#define NN 4096
#define MM 1024
#define BANDP 512

typedef float f4v __attribute__((ext_vector_type(4)));
typedef float f32x4 __attribute__((ext_vector_type(4)));
typedef short bf16x8 __attribute__((ext_vector_type(8)));
typedef short s4v __attribute__((ext_vector_type(4)));

__device__ __forceinline__ short f2b(float f) {
    union { float f; unsigned u; } v; v.f = f;
    unsigned r = v.u + 0x7fffu + ((v.u >> 16) & 1u);
    return (short)(r >> 16);
}
__device__ __forceinline__ float b2f(short s) {
    union { unsigned u; float f; } v;
    v.u = ((unsigned)(unsigned short)s) << 16;
    return v.f;
}

__device__ __forceinline__ void gl2lds16(const void* g, void* l) {
    __builtin_amdgcn_global_load_lds(
        (const __attribute__((address_space(1))) void*)g,
        (__attribute__((address_space(3))) void*)l, 16, 0, 0);
}

// ---------------- x (fp32) -> bf16 hi/lo split ------------------------------
__global__ __launch_bounds__(256)
void split_x_k(const float* __restrict__ s, short* __restrict__ h,
               short* __restrict__ l)
{
    const int i = (blockIdx.x * 256 + threadIdx.x) << 2;
    f4v v = *(const f4v*)&s[i];
    s4v hv, lv;
    #pragma unroll
    for (int q = 0; q < 4; ++q) {
        hv[q] = f2b(v[q]);
        lv[q] = f2b(v[q] - b2f(hv[q]));
    }
    *(s4v*)&h[i] = hv;
    *(s4v*)&l[i] = lv;
}

// ---------------- fp32 weight -> transposed bf16 hi/lo ----------------------
__global__ __launch_bounds__(256)
void trsplit_k(const float* __restrict__ W, short* __restrict__ Th,
               short* __restrict__ Tl)
{
    __shared__ float tile[32][33];
    const int bx = blockIdx.x << 5, by = blockIdx.y << 5;
    const int tx = threadIdx.x, ty = threadIdx.y;
    #pragma unroll
    for (int r = ty; r < 32; r += 8)
        tile[r][tx] = W[(size_t)(by + r) * MM + bx + tx];
    __syncthreads();
    #pragma unroll
    for (int r = ty; r < 32; r += 8) {
        const float v = tile[tx][r];
        const short h = f2b(v);
        Th[(size_t)(bx + r) * MM + by + tx] = h;
        Tl[(size_t)(bx + r) * MM + by + tx] = f2b(v - b2f(h));
    }
}

// ---------------- fp32 weight -> transposed bf16 (single) -------------------
__global__ __launch_bounds__(256)
void transpose_f32_bf16(const float* __restrict__ W, short* __restrict__ Wt)
{
    __shared__ float tile[32][33];
    const int bx = blockIdx.x << 5, by = blockIdx.y << 5;
    const int tx = threadIdx.x, ty = threadIdx.y;
    #pragma unroll
    for (int r = ty; r < 32; r += 8)
        tile[r][tx] = W[(size_t)(by + r) * MM + bx + tx];
    __syncthreads();
    #pragma unroll
    for (int r = ty; r < 32; r += 8)
        Wt[(size_t)(bx + r) * MM + by + tx] = f2b(tile[tx][r]);
}

// ---------------- split-bf16 3-term MFMA GEMM (fp32-faithful path) ----------
// C = (Ah+Al)[MxK] @ (Bh+Bl)^T[NxK], dropping Al*Bl. Out: bf16 hi/lo pair.
template<bool BIAS>
__global__ __launch_bounds__(256, 2)
void gemm_split(const short* __restrict__ Ah, const short* __restrict__ Al,
                const short* __restrict__ Bth, const short* __restrict__ Btl,
                const float* __restrict__ bias0, const float* __restrict__ bias1,
                short* __restrict__ outH, short* __restrict__ outL, int N)
{
    __shared__ short As[2][2][128 * 32];
    __shared__ short Bs[2][2][128 * 32];

    const int t  = threadIdx.x;
    const int l  = t & 63;
    const int w  = t >> 6;
    const int wm = w >> 1, wn = w & 1;
    const int lr = l & 15;
    const int lk = (l >> 4) << 3;

    const int i0 = blockIdx.y << 7;
    const int bn = blockIdx.x << 7;

    const int sr = t >> 2;
    const int sk = (t & 3) << 3;

    const short* aH = Ah  + (size_t)(i0 + sr) * MM + sk;
    const short* aL = Al  + (size_t)(i0 + sr) * MM + sk;
    const short* bH = Bth + (size_t)(bn + sr) * MM + sk;
    const short* bL = Btl + (size_t)(bn + sr) * MM + sk;

    f32x4 acc[4][4] = {};

    auto stage = [&](int sb, int k0) {
        gl2lds16(aH + k0,           &As[sb][0][t * 8]);
        gl2lds16(aH + 64 * MM + k0, &As[sb][0][2048 + t * 8]);
        gl2lds16(aL + k0,           &As[sb][1][t * 8]);
        gl2lds16(aL + 64 * MM + k0, &As[sb][1][2048 + t * 8]);
        gl2lds16(bH + k0,           &Bs[sb][0][t * 8]);
        gl2lds16(bH + 64 * MM + k0, &Bs[sb][0][2048 + t * 8]);
        gl2lds16(bL + k0,           &Bs[sb][1][t * 8]);
        gl2lds16(bL + 64 * MM + k0, &Bs[sb][1][2048 + t * 8]);
    };
    stage(0, 0);
    __syncthreads();

    for (int kt = 0; kt < 32; ++kt) {
        const int cur = kt & 1;
        if (kt + 1 < 32) stage(cur ^ 1, (kt + 1) << 5);
        bf16x8 ah[4], al[4], bh[4], bl[4];
        #pragma unroll
        for (int i = 0; i < 4; ++i) {
            ah[i] = *(const bf16x8*)&As[cur][0][(wm * 64 + i * 16 + lr) * 32 + lk];
            al[i] = *(const bf16x8*)&As[cur][1][(wm * 64 + i * 16 + lr) * 32 + lk];
        }
        #pragma unroll
        for (int j = 0; j < 4; ++j) {
            bh[j] = *(const bf16x8*)&Bs[cur][0][(wn * 64 + j * 16 + lr) * 32 + lk];
            bl[j] = *(const bf16x8*)&Bs[cur][1][(wn * 64 + j * 16 + lr) * 32 + lk];
        }
        #pragma unroll
        for (int i = 0; i < 4; ++i)
            #pragma unroll
            for (int j = 0; j < 4; ++j) {
                acc[i][j] = __builtin_amdgcn_mfma_f32_16x16x32_bf16(ah[i], bl[j], acc[i][j], 0, 0, 0);
                acc[i][j] = __builtin_amdgcn_mfma_f32_16x16x32_bf16(al[i], bh[j], acc[i][j], 0, 0, 0);
                acc[i][j] = __builtin_amdgcn_mfma_f32_16x16x32_bf16(ah[i], bh[j], acc[i][j], 0, 0, 0);
            }
        __syncthreads();
    }

    const int rb = (l >> 4) << 2;
    #pragma unroll
    for (int i = 0; i < 4; ++i)
        #pragma unroll
        for (int j = 0; j < 4; ++j) {
            const int n = bn + wn * 64 + j * 16 + lr;
            float bv = 0.f;
            if (BIAS) bv = (n < 1024) ? bias0[n] : bias1[n - 1024];
            #pragma unroll
            for (int r = 0; r < 4; ++r) {
                const int m = i0 + wm * 64 + i * 16 + rb + r;
                const float v = acc[i][j][r] + bv;
                const short h = f2b(v);
                outH[(size_t)m * N + n] = h;
                outL[(size_t)m * N + n] = f2b(v - b2f(h));
            }
        }
}

// ---------------- bilinear grid sample from bf16 x (hi/lo coords) -----------
__global__ __launch_bounds__(256)
void grid_sample_k(const short* __restrict__ xh, const short* __restrict__ ofh,
                   const short* __restrict__ ofl, short* __restrict__ xnb)
{
    const int i = blockIdx.x;
    const int tid = threadIdx.x;
    const int j4 = tid << 2;

    const short* rh = ofh + (size_t)i * 2048;
    const short* rl = ofl + (size_t)i * 2048;
    s4v hx = *(const s4v*)&rh[j4];
    s4v lx = *(const s4v*)&rl[j4];
    s4v hy = *(const s4v*)&rh[1024 + j4];
    s4v ly = *(const s4v*)&rl[1024 + j4];
    s4v out;

    const float gxb = (2.0f * (float)i) / (float)NN - 1.0f;

    #pragma unroll
    for (int q = 0; q < 4; ++q) {
        const int j = j4 + q;
        float gx = gxb + b2f(hx[q]) + b2f(lx[q]);
        gx = fminf(fmaxf(gx, -1.0f), 1.0f);
        float gy = (2.0f * (float)j) / (float)MM - 1.0f + b2f(hy[q]) + b2f(ly[q]);
        gy = fminf(fmaxf(gy, -1.0f), 1.0f);

        const float ixf = (gx + 1.0f) * 511.5f;
        const float iyf = (gy + 1.0f) * 2047.5f;
        const float ix0 = floorf(ixf);
        const float iy0 = floorf(iyf);
        const float wx = ixf - ix0;
        const float wy = iyf - iy0;
        int ix0i = (int)ix0; ix0i = max(0, min(ix0i, MM - 1));
        int iy0i = (int)iy0; iy0i = max(0, min(iy0i, NN - 1));
        const int ix1i = min(ix0i + 1, MM - 1);
        const int iy1i = min(iy0i + 1, NN - 1);

        const short* r0 = xh + (size_t)iy0i * MM;
        const short* r1 = xh + (size_t)iy1i * MM;
        const float v00 = b2f(r0[ix0i]), v01 = b2f(r0[ix1i]);
        const float v10 = b2f(r1[ix0i]), v11 = b2f(r1[ix1i]);
        out[q] = f2b((1.0f - wy) * ((1.0f - wx) * v00 + wx * v01)
                   + wy * ((1.0f - wx) * v10 + wx * v11));
    }
    *(s4v*)&xnb[(size_t)i * MM + j4] = out;
}

// ---------------- bf16 MFMA GEMM, A[4096x1024] @ Bt^T -----------------------
// MODE 2: C0 fp32 row-major [4096][1024]
// MODE 3: banded logits -> C0 band fp32 [4096][512] with -inf mask; Bt=K
// MODE 4: fused K|V: n<1024 -> C0 = K bf16 [4096][1024]; else C1 = Vt bf16 [1024][4096]
template<int MODE>
__global__ __launch_bounds__(256, 2)
void mfma_gemm(const short* __restrict__ A, const short* __restrict__ Bt,
               void* __restrict__ C0, void* __restrict__ C1)
{
    __shared__ short As[2][128 * 32];
    __shared__ short Bs[2][128 * 32];

    const int t  = threadIdx.x;
    const int l  = t & 63;
    const int w  = t >> 6;
    const int wm = w >> 1, wn = w & 1;
    const int lr = l & 15;
    const int lk = (l >> 4) << 3;

    const int i0 = blockIdx.y << 7;
    const int bn = blockIdx.x << 7;
    const int jb = (MODE == 3) ? (i0 - 256 + bn) : bn;

    const int sr = t >> 2;
    const int sk = (t & 3) << 3;

    const short* aS = A + (size_t)(i0 + sr) * MM + sk;
    int br0 = jb + sr, br1 = jb + sr + 64;
    if (MODE == 3) {
        br0 = min(max(br0, 0), NN - 1);
        br1 = min(max(br1, 0), NN - 1);
    }
    const short* bS0 = Bt + (size_t)br0 * MM + sk;
    const short* bS1 = Bt + (size_t)br1 * MM + sk;

    f32x4 acc[4][4] = {};

    auto stage = [&](int sb, int k0) {
        gl2lds16(aS + k0,           &As[sb][0] + t * 8);
        gl2lds16(aS + 64 * MM + k0, &As[sb][0] + 2048 + t * 8);
        gl2lds16(bS0 + k0,          &Bs[sb][0] + t * 8);
        gl2lds16(bS1 + k0,          &Bs[sb][0] + 2048 + t * 8);
    };
    stage(0, 0);
    __syncthreads();

    for (int kt = 0; kt < 32; ++kt) {
        const int cur = kt & 1;
        if (kt + 1 < 32) stage(cur ^ 1, (kt + 1) << 5);
        bf16x8 a[4], b[4];
        #pragma unroll
        for (int i = 0; i < 4; ++i)
            a[i] = *(const bf16x8*)&As[cur][(wm * 64 + i * 16 + lr) * 32 + lk];
        #pragma unroll
        for (int j = 0; j < 4; ++j)
            b[j] = *(const bf16x8*)&Bs[cur][(wn * 64 + j * 16 + lr) * 32 + lk];
        #pragma unroll
        for (int i = 0; i < 4; ++i)
            #pragma unroll
            for (int j = 0; j < 4; ++j)
                acc[i][j] = __builtin_amdgcn_mfma_f32_16x16x32_bf16(a[i], b[j], acc[i][j], 0, 0, 0);
        __syncthreads();
    }

    const int rb = (l >> 4) << 2;
    #pragma unroll
    for (int i = 0; i < 4; ++i) {
        #pragma unroll
        for (int j = 0; j < 4; ++j) {
            const int nl = wn * 64 + j * 16 + lr;
            if (MODE == 4 && bn + nl >= 1024) {
                const int m0 = i0 + wm * 64 + i * 16 + rb;
                s4v o;
                #pragma unroll
                for (int r = 0; r < 4; ++r) o[r] = f2b(acc[i][j][r]);
                *(s4v*)&((short*)C1)[(size_t)(bn + nl - 1024) * NN + m0] = o;
            } else {
                #pragma unroll
                for (int r = 0; r < 4; ++r) {
                    const int m = i0 + wm * 64 + i * 16 + rb + r;
                    const float v = acc[i][j][r];
                    if (MODE == 4) {
                        ((short*)C0)[(size_t)m * MM + bn + nl] = f2b(v);
                    } else if (MODE == 2) {
                        ((float*)C0)[(size_t)m * MM + bn + nl] = v;
                    } else if (MODE == 3) {
                        const int jj = jb + nl;
                        const int ci = jj - m + 255;
                        if (ci >= 0 && ci <= 510)
                            ((float*)C0)[(size_t)m * BANDP + ci] =
                                (jj >= 0 && jj < NN) ? 0.06f * v : -INFINITY;
                    }
                }
            }
        }
    }
}

// ---------------- softmax over band; writes att rows + bandT scatter --------
__global__ __launch_bounds__(256)
void band_softmax(const float* __restrict__ band, float* __restrict__ att,
                  short* __restrict__ bandT)
{
    const int i = blockIdx.x;
    const int tid = threadIdx.x;
    const float* brow = band + (size_t)i * BANDP;

    float v0 = brow[tid];
    float v1 = (tid < 255) ? brow[tid + 256] : -INFINITY;

    float m = fmaxf(v0, v1);
    #pragma unroll
    for (int o = 32; o >= 1; o >>= 1) m = fmaxf(m, __shfl_xor(m, o));
    __shared__ float redm[4], reds[4];
    const int wv = tid >> 6, ln = tid & 63;
    if (ln == 0) redm[wv] = m;
    __syncthreads();
    m = fmaxf(fmaxf(redm[0], redm[1]), fmaxf(redm[2], redm[3]));

    float p0 = expf(v0 - m);
    float p1 = (tid < 255) ? expf(v1 - m) : 0.f;
    float s = p0 + p1;
    #pragma unroll
    for (int o = 32; o >= 1; o >>= 1) s += __shfl_xor(s, o);
    if (ln == 0) reds[wv] = s;
    __syncthreads();
    s = reds[0] + reds[1] + reds[2] + reds[3];
    const float rinv = 1.0f / s;
    p0 *= rinv; p1 *= rinv;

    float* arow = att + (size_t)i * NN;
    f4v z = {0.f, 0.f, 0.f, 0.f};
    #pragma unroll
    for (int q = 0; q < 4; ++q)
        *(f4v*)&arow[(q * 256 + tid) << 2] = z;
    __syncthreads();
    int j = i + tid - 255;
    if (j >= 0 && j < NN) {
        arow[j] = p0;
        bandT[(size_t)j * 768 + (i - (j & ~7) + 384)] = f2b(p0);
    }
    j = i + tid + 1;
    if (tid < 255 && j >= 0 && j < NN) {
        arow[j] = p1;
        bandT[(size_t)j * 768 + (i - (j & ~7) + 384)] = f2b(p1);
    }
}

// ---------------- y1 = att^T @ V via MFMA, direct-global operands -----------
__global__ __launch_bounds__(256, 2)
void attT_v_mfma(const short* __restrict__ bandT, const short* __restrict__ Vt,
                 short* __restrict__ y1b)
{
    const int t = threadIdx.x, l = t & 63, w = t >> 6;
    const int wm = w >> 1, wn = w & 1;
    const int lr = l & 15, lk = (l >> 4) << 3;
    const int r0 = blockIdx.y << 7;
    const int n0 = blockIdx.x << 6;

    f32x4 acc[4][2] = {};
    for (int ks = 0; ks < 20; ++ks) {
        const int j0 = r0 - 256 + (ks << 5);
        if (j0 < 0 || j0 >= NN) continue;
        bf16x8 b[2];
        #pragma unroll
        for (int j = 0; j < 2; ++j)
            b[j] = *(const bf16x8*)&Vt[(size_t)(n0 + wn * 32 + j * 16 + lr) * NN + j0 + lk];
        #pragma unroll
        for (int i = 0; i < 4; ++i) {
            const int r = r0 + wm * 64 + i * 16 + lr;
            const int cc = j0 + lk - (r & ~7) + 384;
            bf16x8 a = *(const bf16x8*)&bandT[(size_t)r * 768 + cc];
            #pragma unroll
            for (int j = 0; j < 2; ++j)
                acc[i][j] = __builtin_amdgcn_mfma_f32_16x16x32_bf16(a, b[j], acc[i][j], 0, 0, 0);
        }
    }
    const int rb = (l >> 4) << 2;
    #pragma unroll
    for (int i = 0; i < 4; ++i)
        #pragma unroll
        for (int j = 0; j < 2; ++j)
            #pragma unroll
            for (int r = 0; r < 4; ++r)
                y1b[(size_t)(r0 + wm * 64 + i * 16 + rb + r) * MM + n0 + wn * 32 + j * 16 + lr]
                    = f2b(acc[i][j][r]);
}

extern "C" void kernel_launch(void* const* d_in, const int* in_sizes, int n_in,
                              void* d_out, int out_size, void* d_ws, size_t ws_size,
                              hipStream_t stream)
{
    const float* x    = (const float*)d_in[0];
    const float* Wq   = (const float*)d_in[1];
    const float* Wk   = (const float*)d_in[2];
    const float* Wv   = (const float*)d_in[3];
    const float* Wofx = (const float*)d_in[4];
    const float* bofx = (const float*)d_in[5];
    const float* Wofy = (const float*)d_in[6];
    const float* bofy = (const float*)d_in[7];
    const float* Wout = (const float*)d_in[8];

    float* y_out   = (float*)d_out;
    float* att_out = (float*)d_out + (size_t)NN * MM;

    char* wsb = (char*)d_ws;
    const size_t MB = 1024 * 1024;
    // Liveness-verified layout (MB ranges), peak 64 MB at the ofxy-GEMM step:
    //  split_x:     -> xh[0,8) xl[24,32)
    //  trsplit Wq:  -> WqT[32,36)
    //  Q-GEMM:      reads xh xl WqT -> Qh[8,16) Ql[16,24)      (xl,WqT dead)
    //  trsplit ofxy:-> WofxyT[24,32)  (over xl)
    //  ofxy-GEMM:   reads Qh Ql WofxyT -> ofxyh[32,48) ofxyl[48,64)
    //               (Ql, WofxyT dead; xh STILL LIVE)
    //  grid_sample: reads xh ofxyh ofxyl -> xnb[16,24)          (xh, ofxy* dead)
    //  transposes:  -> WkvT[0,4) WoutT[4,6)   (over xh, dead)
    //  KV-GEMM:     reads xnb WkvT -> Kb[24,32) Vtb[32,40)      (xnb, WkvT dead)
    //  logits:      reads Qh Kb -> band[40,48)                  (Qh dead after)
    //  softmax:     reads band -> att_out, bandT[48,54)         (band dead)
    //  attT_v:      reads bandT Vtb -> y1b[16,24)  (over xnb, dead)
    //  final:       reads y1b WoutT[4,6) -> y_out
    short* xh      = (short*)(wsb + 0);
    short* Qh      = (short*)(wsb + 8 * MB);
    short* Ql      = (short*)(wsb + 16 * MB);
    short* xl      = (short*)(wsb + 24 * MB);
    short* WqTh    = (short*)(wsb + 32 * MB);
    short* WqTl    = (short*)(wsb + 34 * MB);
    short* WofxyTh = (short*)(wsb + 24 * MB);   // over xl (dead)
    short* WofxyTl = (short*)(wsb + 28 * MB);
    short* ofxyh   = (short*)(wsb + 32 * MB);   // over WqT (dead)
    short* ofxyl   = (short*)(wsb + 48 * MB);
    short* xnb     = (short*)(wsb + 16 * MB);   // over Ql (dead)
    short* WkvT    = (short*)(wsb + 0);         // over xh (dead)
    short* WoutT   = (short*)(wsb + 4 * MB);
    short* Kb      = (short*)(wsb + 24 * MB);   // over WofxyT (dead)
    short* Vtb     = (short*)(wsb + 32 * MB);   // over ofxyh (dead)
    float* band    = (float*)(wsb + 40 * MB);
    short* bandT   = (short*)(wsb + 48 * MB);   // over ofxyl (dead)
    short* y1b     = (short*)(wsb + 16 * MB);   // over xnb (dead)

    const dim3 blk(256);
    const dim3 tgrid(32, 32), tblk(32, 8);

    // ---- sensitive path via split-bf16 MFMA ----
    split_x_k<<<dim3(4096), blk, 0, stream>>>(x, xh, xl);
    trsplit_k<<<tgrid, tblk, 0, stream>>>(Wq, WqTh, WqTl);
    gemm_split<false><<<dim3(8, 32), blk, 0, stream>>>(
        xh, xl, WqTh, WqTl, nullptr, nullptr, Qh, Ql, 1024);
    trsplit_k<<<tgrid, tblk, 0, stream>>>(Wofx, WofxyTh, WofxyTl);
    trsplit_k<<<tgrid, tblk, 0, stream>>>(Wofy, WofxyTh + 1024 * 1024, WofxyTl + 1024 * 1024);
    gemm_split<true><<<dim3(16, 32), blk, 0, stream>>>(
        Qh, Ql, WofxyTh, WofxyTl, bofx, bofy, ofxyh, ofxyl, 2048);

    // gather from bf16 x (xh) — halves gather footprint & line amplification
    grid_sample_k<<<dim3(NN), blk, 0, stream>>>(xh, ofxyh, ofxyl, xnb);

    // ---- bf16 path ----
    transpose_f32_bf16<<<tgrid, tblk, 0, stream>>>(Wk, WkvT);
    transpose_f32_bf16<<<tgrid, tblk, 0, stream>>>(Wv, WkvT + 1024 * 1024);
    transpose_f32_bf16<<<tgrid, tblk, 0, stream>>>(Wout, WoutT);

    // K | Vt fused
    mfma_gemm<4><<<dim3(16, 32), blk, 0, stream>>>(xnb, WkvT, Kb, Vtb);
    // banded logits
    mfma_gemm<3><<<dim3(5, 32), blk, 0, stream>>>(Qh, Kb, band, nullptr);
    // softmax -> att rows in d_out + bandT bf16 scatter
    hipMemsetAsync(bandT, 0, (size_t)NN * 768 * sizeof(short), stream);
    band_softmax<<<dim3(NN), blk, 0, stream>>>(band, att_out, bandT);
    // y1 = att^T @ V
    attT_v_mfma<<<dim3(16, 32), blk, 0, stream>>>(bandT, Vtb, y1b);
    // y = y1 @ Wout
    mfma_gemm<2><<<dim3(8, 32), blk, 0, stream>>>(y1b, WoutT, y_out, nullptr);
}

// Round 6
// 328.864 us; speedup vs baseline: 2.9769x; 1.0170x over previous
//
#include <hip/hip_runtime.h>
#include <hip/hip_bf16.h>
#include <math.h>

#define NN 4096
#define MM 1024
#define BANDP 512

typedef float f4v __attribute__((ext_vector_type(4)));
typedef float f32x4 __attribute__((ext_vector_type(4)));
typedef short bf16x8 __attribute__((ext_vector_type(8)));
typedef short s4v __attribute__((ext_vector_type(4)));

__device__ __forceinline__ short f2b(float f) {
    union { float f; unsigned u; } v; v.f = f;
    unsigned r = v.u + 0x7fffu + ((v.u >> 16) & 1u);
    return (short)(r >> 16);
}
__device__ __forceinline__ float b2f(short s) {
    union { unsigned u; float f; } v;
    v.u = ((unsigned)(unsigned short)s) << 16;
    return v.f;
}

__device__ __forceinline__ void gl2lds16(const void* g, void* l) {
    __builtin_amdgcn_global_load_lds(
        (const __attribute__((address_space(1))) void*)g,
        (__attribute__((address_space(3))) void*)l, 16, 0, 0);
}

#define WAIT_VM8() asm volatile("s_waitcnt vmcnt(8)" ::: "memory")
#define WAIT_VM4() asm volatile("s_waitcnt vmcnt(4)" ::: "memory")
#define WAIT_VM0() asm volatile("s_waitcnt vmcnt(0)" ::: "memory")

// ---------------- x (fp32) -> bf16 hi/lo split ------------------------------
__global__ __launch_bounds__(256)
void split_x_k(const float* __restrict__ s, short* __restrict__ h,
               short* __restrict__ l)
{
    const int i = (blockIdx.x * 256 + threadIdx.x) << 2;
    f4v v = *(const f4v*)&s[i];
    s4v hv, lv;
    #pragma unroll
    for (int q = 0; q < 4; ++q) {
        hv[q] = f2b(v[q]);
        lv[q] = f2b(v[q] - b2f(hv[q]));
    }
    *(s4v*)&h[i] = hv;
    *(s4v*)&l[i] = lv;
}

// ---------------- fp32 weight -> transposed bf16 hi/lo ----------------------
__global__ __launch_bounds__(256)
void trsplit_k(const float* __restrict__ W, short* __restrict__ Th,
               short* __restrict__ Tl)
{
    __shared__ float tile[32][33];
    const int bx = blockIdx.x << 5, by = blockIdx.y << 5;
    const int tx = threadIdx.x, ty = threadIdx.y;
    #pragma unroll
    for (int r = ty; r < 32; r += 8)
        tile[r][tx] = W[(size_t)(by + r) * MM + bx + tx];
    __syncthreads();
    #pragma unroll
    for (int r = ty; r < 32; r += 8) {
        const float v = tile[tx][r];
        const short h = f2b(v);
        Th[(size_t)(bx + r) * MM + by + tx] = h;
        Tl[(size_t)(bx + r) * MM + by + tx] = f2b(v - b2f(h));
    }
}

// ---------------- fp32 weight -> transposed bf16 (single) -------------------
__global__ __launch_bounds__(256)
void transpose_f32_bf16(const float* __restrict__ W, short* __restrict__ Wt)
{
    __shared__ float tile[32][33];
    const int bx = blockIdx.x << 5, by = blockIdx.y << 5;
    const int tx = threadIdx.x, ty = threadIdx.y;
    #pragma unroll
    for (int r = ty; r < 32; r += 8)
        tile[r][tx] = W[(size_t)(by + r) * MM + bx + tx];
    __syncthreads();
    #pragma unroll
    for (int r = ty; r < 32; r += 8)
        Wt[(size_t)(bx + r) * MM + by + tx] = f2b(tile[tx][r]);
}

// ---------------- split-bf16 3-term MFMA GEMM (fp32-faithful path) ----------
// Counted-vmcnt raw-barrier pipeline + LDS XOR swizzle + setprio.
// LDS tile rows are 64B; swizzle: slot(16B) ^= (row>>1)&3. Staged linear via
// gl2lds with inverse-swizzled GLOBAL source col; reads apply same XOR.
template<bool BIAS>
__global__ __launch_bounds__(256, 2)
void gemm_split(const short* __restrict__ Ah, const short* __restrict__ Al,
                const short* __restrict__ Bth, const short* __restrict__ Btl,
                const float* __restrict__ bias0, const float* __restrict__ bias1,
                short* __restrict__ outH, short* __restrict__ outL, int N)
{
    __shared__ short As[2][2][128 * 32];
    __shared__ short Bs[2][2][128 * 32];

    const int t  = threadIdx.x;
    const int l  = t & 63;
    const int w  = t >> 6;
    const int wm = w >> 1, wn = w & 1;
    const int lr = l & 15;
    const int lk = (l >> 4) << 3;
    const int lks = lk ^ (((l >> 1) & 3) << 3);   // swizzled read col (elems)

    const int i0 = blockIdx.y << 7;
    const int bn = blockIdx.x << 7;

    const int sr = t >> 2;
    const int sk = (((t & 3) ^ ((t >> 3) & 3)) << 3);  // inverse-swz source col

    const short* aH = Ah  + (size_t)(i0 + sr) * MM + sk;
    const short* aL = Al  + (size_t)(i0 + sr) * MM + sk;
    const short* bH = Bth + (size_t)(bn + sr) * MM + sk;
    const short* bL = Btl + (size_t)(bn + sr) * MM + sk;

    f32x4 acc[4][4] = {};

    auto stage = [&](int sb, int k0) {
        gl2lds16(aH + k0,           &As[sb][0][t * 8]);
        gl2lds16(aH + 64 * MM + k0, &As[sb][0][2048 + t * 8]);
        gl2lds16(aL + k0,           &As[sb][1][t * 8]);
        gl2lds16(aL + 64 * MM + k0, &As[sb][1][2048 + t * 8]);
        gl2lds16(bH + k0,           &Bs[sb][0][t * 8]);
        gl2lds16(bH + 64 * MM + k0, &Bs[sb][0][2048 + t * 8]);
        gl2lds16(bL + k0,           &Bs[sb][1][t * 8]);
        gl2lds16(bL + 64 * MM + k0, &Bs[sb][1][2048 + t * 8]);
    };
    stage(0, 0);

    for (int kt = 0; kt < 32; ++kt) {
        const int cur = kt & 1;
        if (kt + 1 < 32) { stage(cur ^ 1, (kt + 1) << 5); WAIT_VM8(); }
        else             { WAIT_VM0(); }
        __builtin_amdgcn_s_barrier();
        __builtin_amdgcn_sched_barrier(0);

        bf16x8 ah[4], al[4], bh[4], bl[4];
        #pragma unroll
        for (int i = 0; i < 4; ++i) {
            ah[i] = *(const bf16x8*)&As[cur][0][(wm * 64 + i * 16 + lr) * 32 + lks];
            al[i] = *(const bf16x8*)&As[cur][1][(wm * 64 + i * 16 + lr) * 32 + lks];
        }
        #pragma unroll
        for (int j = 0; j < 4; ++j) {
            bh[j] = *(const bf16x8*)&Bs[cur][0][(wn * 64 + j * 16 + lr) * 32 + lks];
            bl[j] = *(const bf16x8*)&Bs[cur][1][(wn * 64 + j * 16 + lr) * 32 + lks];
        }
        __builtin_amdgcn_s_setprio(1);
        #pragma unroll
        for (int i = 0; i < 4; ++i)
            #pragma unroll
            for (int j = 0; j < 4; ++j) {
                acc[i][j] = __builtin_amdgcn_mfma_f32_16x16x32_bf16(ah[i], bl[j], acc[i][j], 0, 0, 0);
                acc[i][j] = __builtin_amdgcn_mfma_f32_16x16x32_bf16(al[i], bh[j], acc[i][j], 0, 0, 0);
                acc[i][j] = __builtin_amdgcn_mfma_f32_16x16x32_bf16(ah[i], bh[j], acc[i][j], 0, 0, 0);
            }
        __builtin_amdgcn_s_setprio(0);
        __builtin_amdgcn_s_barrier();
    }

    const int rb = (l >> 4) << 2;
    #pragma unroll
    for (int i = 0; i < 4; ++i)
        #pragma unroll
        for (int j = 0; j < 4; ++j) {
            const int n = bn + wn * 64 + j * 16 + lr;
            float bv = 0.f;
            if (BIAS) bv = (n < 1024) ? bias0[n] : bias1[n - 1024];
            #pragma unroll
            for (int r = 0; r < 4; ++r) {
                const int m = i0 + wm * 64 + i * 16 + rb + r;
                const float v = acc[i][j][r] + bv;
                const short h = f2b(v);
                outH[(size_t)m * N + n] = h;
                outL[(size_t)m * N + n] = f2b(v - b2f(h));
            }
        }
}

// ---------------- bilinear grid sample from bf16 x (hi/lo coords) -----------
__global__ __launch_bounds__(256)
void grid_sample_k(const short* __restrict__ xh, const short* __restrict__ ofh,
                   const short* __restrict__ ofl, short* __restrict__ xnb)
{
    const int i = blockIdx.x;
    const int tid = threadIdx.x;
    const int j4 = tid << 2;

    const short* rh = ofh + (size_t)i * 2048;
    const short* rl = ofl + (size_t)i * 2048;
    s4v hx = *(const s4v*)&rh[j4];
    s4v lx = *(const s4v*)&rl[j4];
    s4v hy = *(const s4v*)&rh[1024 + j4];
    s4v ly = *(const s4v*)&rl[1024 + j4];
    s4v out;

    const float gxb = (2.0f * (float)i) / (float)NN - 1.0f;

    #pragma unroll
    for (int q = 0; q < 4; ++q) {
        const int j = j4 + q;
        float gx = gxb + b2f(hx[q]) + b2f(lx[q]);
        gx = fminf(fmaxf(gx, -1.0f), 1.0f);
        float gy = (2.0f * (float)j) / (float)MM - 1.0f + b2f(hy[q]) + b2f(ly[q]);
        gy = fminf(fmaxf(gy, -1.0f), 1.0f);

        const float ixf = (gx + 1.0f) * 511.5f;
        const float iyf = (gy + 1.0f) * 2047.5f;
        const float ix0 = floorf(ixf);
        const float iy0 = floorf(iyf);
        const float wx = ixf - ix0;
        const float wy = iyf - iy0;
        int ix0i = (int)ix0; ix0i = max(0, min(ix0i, MM - 1));
        int iy0i = (int)iy0; iy0i = max(0, min(iy0i, NN - 1));
        const int ix1i = min(ix0i + 1, MM - 1);
        const int iy1i = min(iy0i + 1, NN - 1);

        const short* r0 = xh + (size_t)iy0i * MM;
        const short* r1 = xh + (size_t)iy1i * MM;
        const float v00 = b2f(r0[ix0i]), v01 = b2f(r0[ix1i]);
        const float v10 = b2f(r1[ix0i]), v11 = b2f(r1[ix1i]);
        out[q] = f2b((1.0f - wy) * ((1.0f - wx) * v00 + wx * v01)
                   + wy * ((1.0f - wx) * v10 + wx * v11));
    }
    *(s4v*)&xnb[(size_t)i * MM + j4] = out;
}

// ---------------- bf16 MFMA GEMM, A[4096x1024] @ Bt^T -----------------------
// Counted-vmcnt raw-barrier pipeline + LDS XOR swizzle + setprio.
// MODE 2: C0 fp32 row-major [4096][1024]
// MODE 3: banded logits -> C0 band fp32 [4096][512] with -inf mask; Bt=K
// MODE 4: fused K|V: n<1024 -> C0 = K bf16 [4096][1024]; else C1 = Vt bf16 [1024][4096]
template<int MODE>
__global__ __launch_bounds__(256, 2)
void mfma_gemm(const short* __restrict__ A, const short* __restrict__ Bt,
               void* __restrict__ C0, void* __restrict__ C1)
{
    __shared__ short As[2][128 * 32];
    __shared__ short Bs[2][128 * 32];

    const int t  = threadIdx.x;
    const int l  = t & 63;
    const int w  = t >> 6;
    const int wm = w >> 1, wn = w & 1;
    const int lr = l & 15;
    const int lk = (l >> 4) << 3;
    const int lks = lk ^ (((l >> 1) & 3) << 3);

    const int i0 = blockIdx.y << 7;
    const int bn = blockIdx.x << 7;
    const int jb = (MODE == 3) ? (i0 - 256 + bn) : bn;

    const int sr = t >> 2;
    const int sk = (((t & 3) ^ ((t >> 3) & 3)) << 3);

    const short* aS = A + (size_t)(i0 + sr) * MM + sk;
    int br0 = jb + sr, br1 = jb + sr + 64;
    if (MODE == 3) {
        br0 = min(max(br0, 0), NN - 1);
        br1 = min(max(br1, 0), NN - 1);
    }
    const short* bS0 = Bt + (size_t)br0 * MM + sk;
    const short* bS1 = Bt + (size_t)br1 * MM + sk;

    f32x4 acc[4][4] = {};

    auto stage = [&](int sb, int k0) {
        gl2lds16(aS + k0,           &As[sb][0] + t * 8);
        gl2lds16(aS + 64 * MM + k0, &As[sb][0] + 2048 + t * 8);
        gl2lds16(bS0 + k0,          &Bs[sb][0] + t * 8);
        gl2lds16(bS1 + k0,          &Bs[sb][0] + 2048 + t * 8);
    };
    stage(0, 0);

    for (int kt = 0; kt < 32; ++kt) {
        const int cur = kt & 1;
        if (kt + 1 < 32) { stage(cur ^ 1, (kt + 1) << 5); WAIT_VM4(); }
        else             { WAIT_VM0(); }
        __builtin_amdgcn_s_barrier();
        __builtin_amdgcn_sched_barrier(0);

        bf16x8 a[4], b[4];
        #pragma unroll
        for (int i = 0; i < 4; ++i)
            a[i] = *(const bf16x8*)&As[cur][(wm * 64 + i * 16 + lr) * 32 + lks];
        #pragma unroll
        for (int j = 0; j < 4; ++j)
            b[j] = *(const bf16x8*)&Bs[cur][(wn * 64 + j * 16 + lr) * 32 + lks];
        __builtin_amdgcn_s_setprio(1);
        #pragma unroll
        for (int i = 0; i < 4; ++i)
            #pragma unroll
            for (int j = 0; j < 4; ++j)
                acc[i][j] = __builtin_amdgcn_mfma_f32_16x16x32_bf16(a[i], b[j], acc[i][j], 0, 0, 0);
        __builtin_amdgcn_s_setprio(0);
        __builtin_amdgcn_s_barrier();
    }

    const int rb = (l >> 4) << 2;
    #pragma unroll
    for (int i = 0; i < 4; ++i) {
        #pragma unroll
        for (int j = 0; j < 4; ++j) {
            const int nl = wn * 64 + j * 16 + lr;
            if (MODE == 4 && bn + nl >= 1024) {
                const int m0 = i0 + wm * 64 + i * 16 + rb;
                s4v o;
                #pragma unroll
                for (int r = 0; r < 4; ++r) o[r] = f2b(acc[i][j][r]);
                *(s4v*)&((short*)C1)[(size_t)(bn + nl - 1024) * NN + m0] = o;
            } else {
                #pragma unroll
                for (int r = 0; r < 4; ++r) {
                    const int m = i0 + wm * 64 + i * 16 + rb + r;
                    const float v = acc[i][j][r];
                    if (MODE == 4) {
                        ((short*)C0)[(size_t)m * MM + bn + nl] = f2b(v);
                    } else if (MODE == 2) {
                        ((float*)C0)[(size_t)m * MM + bn + nl] = v;
                    } else if (MODE == 3) {
                        const int jj = jb + nl;
                        const int ci = jj - m + 255;
                        if (ci >= 0 && ci <= 510)
                            ((float*)C0)[(size_t)m * BANDP + ci] =
                                (jj >= 0 && jj < NN) ? 0.06f * v : -INFINITY;
                    }
                }
            }
        }
    }
}

// ---------------- softmax over band; writes att rows + bandT scatter --------
__global__ __launch_bounds__(256)
void band_softmax(const float* __restrict__ band, float* __restrict__ att,
                  short* __restrict__ bandT)
{
    const int i = blockIdx.x;
    const int tid = threadIdx.x;
    const float* brow = band + (size_t)i * BANDP;

    float v0 = brow[tid];
    float v1 = (tid < 255) ? brow[tid + 256] : -INFINITY;

    float m = fmaxf(v0, v1);
    #pragma unroll
    for (int o = 32; o >= 1; o >>= 1) m = fmaxf(m, __shfl_xor(m, o));
    __shared__ float redm[4], reds[4];
    const int wv = tid >> 6, ln = tid & 63;
    if (ln == 0) redm[wv] = m;
    __syncthreads();
    m = fmaxf(fmaxf(redm[0], redm[1]), fmaxf(redm[2], redm[3]));

    float p0 = expf(v0 - m);
    float p1 = (tid < 255) ? expf(v1 - m) : 0.f;
    float s = p0 + p1;
    #pragma unroll
    for (int o = 32; o >= 1; o >>= 1) s += __shfl_xor(s, o);
    if (ln == 0) reds[wv] = s;
    __syncthreads();
    s = reds[0] + reds[1] + reds[2] + reds[3];
    const float rinv = 1.0f / s;
    p0 *= rinv; p1 *= rinv;

    float* arow = att + (size_t)i * NN;
    f4v z = {0.f, 0.f, 0.f, 0.f};
    #pragma unroll
    for (int q = 0; q < 4; ++q)
        *(f4v*)&arow[(q * 256 + tid) << 2] = z;
    __syncthreads();
    int j = i + tid - 255;
    if (j >= 0 && j < NN) {
        arow[j] = p0;
        bandT[(size_t)j * 768 + (i - (j & ~7) + 384)] = f2b(p0);
    }
    j = i + tid + 1;
    if (tid < 255 && j >= 0 && j < NN) {
        arow[j] = p1;
        bandT[(size_t)j * 768 + (i - (j & ~7) + 384)] = f2b(p1);
    }
}

// ---------------- y1 = att^T @ V via MFMA, direct-global operands -----------
__global__ __launch_bounds__(256, 2)
void attT_v_mfma(const short* __restrict__ bandT, const short* __restrict__ Vt,
                 short* __restrict__ y1b)
{
    const int t = threadIdx.x, l = t & 63, w = t >> 6;
    const int wm = w >> 1, wn = w & 1;
    const int lr = l & 15, lk = (l >> 4) << 3;
    const int r0 = blockIdx.y << 7;
    const int n0 = blockIdx.x << 6;

    f32x4 acc[4][2] = {};
    for (int ks = 0; ks < 20; ++ks) {
        const int j0 = r0 - 256 + (ks << 5);
        if (j0 < 0 || j0 >= NN) continue;
        bf16x8 b[2];
        #pragma unroll
        for (int j = 0; j < 2; ++j)
            b[j] = *(const bf16x8*)&Vt[(size_t)(n0 + wn * 32 + j * 16 + lr) * NN + j0 + lk];
        #pragma unroll
        for (int i = 0; i < 4; ++i) {
            const int r = r0 + wm * 64 + i * 16 + lr;
            const int cc = j0 + lk - (r & ~7) + 384;
            bf16x8 a = *(const bf16x8*)&bandT[(size_t)r * 768 + cc];
            #pragma unroll
            for (int j = 0; j < 2; ++j)
                acc[i][j] = __builtin_amdgcn_mfma_f32_16x16x32_bf16(a, b[j], acc[i][j], 0, 0, 0);
        }
    }
    const int rb = (l >> 4) << 2;
    #pragma unroll
    for (int i = 0; i < 4; ++i)
        #pragma unroll
        for (int j = 0; j < 2; ++j)
            #pragma unroll
            for (int r = 0; r < 4; ++r)
                y1b[(size_t)(r0 + wm * 64 + i * 16 + rb + r) * MM + n0 + wn * 32 + j * 16 + lr]
                    = f2b(acc[i][j][r]);
}

extern "C" void kernel_launch(void* const* d_in, const int* in_sizes, int n_in,
                              void* d_out, int out_size, void* d_ws, size_t ws_size,
                              hipStream_t stream)
{
    const float* x    = (const float*)d_in[0];
    const float* Wq   = (const float*)d_in[1];
    const float* Wk   = (const float*)d_in[2];
    const float* Wv   = (const float*)d_in[3];
    const float* Wofx = (const float*)d_in[4];
    const float* bofx = (const float*)d_in[5];
    const float* Wofy = (const float*)d_in[6];
    const float* bofy = (const float*)d_in[7];
    const float* Wout = (const float*)d_in[8];

    float* y_out   = (float*)d_out;
    float* att_out = (float*)d_out + (size_t)NN * MM;

    char* wsb = (char*)d_ws;
    const size_t MB = 1024 * 1024;
    // Liveness-verified layout (MB ranges), peak 64 MB at the ofxy-GEMM step
    // (identical to R5 — proven):
    short* xh      = (short*)(wsb + 0);
    short* Qh      = (short*)(wsb + 8 * MB);
    short* Ql      = (short*)(wsb + 16 * MB);
    short* xl      = (short*)(wsb + 24 * MB);
    short* WqTh    = (short*)(wsb + 32 * MB);
    short* WqTl    = (short*)(wsb + 34 * MB);
    short* WofxyTh = (short*)(wsb + 24 * MB);   // over xl (dead)
    short* WofxyTl = (short*)(wsb + 28 * MB);
    short* ofxyh   = (short*)(wsb + 32 * MB);   // over WqT (dead)
    short* ofxyl   = (short*)(wsb + 48 * MB);
    short* xnb     = (short*)(wsb + 16 * MB);   // over Ql (dead)
    short* WkvT    = (short*)(wsb + 0);         // over xh (dead)
    short* WoutT   = (short*)(wsb + 4 * MB);
    short* Kb      = (short*)(wsb + 24 * MB);   // over WofxyT (dead)
    short* Vtb     = (short*)(wsb + 32 * MB);   // over ofxyh (dead)
    float* band    = (float*)(wsb + 40 * MB);
    short* bandT   = (short*)(wsb + 48 * MB);   // over ofxyl (dead)
    short* y1b     = (short*)(wsb + 16 * MB);   // over xnb (dead)

    const dim3 blk(256);
    const dim3 tgrid(32, 32), tblk(32, 8);

    // ---- sensitive path via split-bf16 MFMA ----
    split_x_k<<<dim3(4096), blk, 0, stream>>>(x, xh, xl);
    trsplit_k<<<tgrid, tblk, 0, stream>>>(Wq, WqTh, WqTl);
    gemm_split<false><<<dim3(8, 32), blk, 0, stream>>>(
        xh, xl, WqTh, WqTl, nullptr, nullptr, Qh, Ql, 1024);
    trsplit_k<<<tgrid, tblk, 0, stream>>>(Wofx, WofxyTh, WofxyTl);
    trsplit_k<<<tgrid, tblk, 0, stream>>>(Wofy, WofxyTh + 1024 * 1024, WofxyTl + 1024 * 1024);
    gemm_split<true><<<dim3(16, 32), blk, 0, stream>>>(
        Qh, Ql, WofxyTh, WofxyTl, bofx, bofy, ofxyh, ofxyl, 2048);

    // gather from bf16 x (xh)
    grid_sample_k<<<dim3(NN), blk, 0, stream>>>(xh, ofxyh, ofxyl, xnb);

    // ---- bf16 path ----
    transpose_f32_bf16<<<tgrid, tblk, 0, stream>>>(Wk, WkvT);
    transpose_f32_bf16<<<tgrid, tblk, 0, stream>>>(Wv, WkvT + 1024 * 1024);
    transpose_f32_bf16<<<tgrid, tblk, 0, stream>>>(Wout, WoutT);

    // K | Vt fused
    mfma_gemm<4><<<dim3(16, 32), blk, 0, stream>>>(xnb, WkvT, Kb, Vtb);
    // banded logits
    mfma_gemm<3><<<dim3(5, 32), blk, 0, stream>>>(Qh, Kb, band, nullptr);
    // softmax -> att rows in d_out + bandT bf16 scatter
    hipMemsetAsync(bandT, 0, (size_t)NN * 768 * sizeof(short), stream);
    band_softmax<<<dim3(NN), blk, 0, stream>>>(band, att_out, bandT);
    // y1 = att^T @ V
    attT_v_mfma<<<dim3(16, 32), blk, 0, stream>>>(bandT, Vtb, y1b);
    // y = y1 @ Wout
    mfma_gemm<2><<<dim3(8, 32), blk, 0, stream>>>(y1b, WoutT, y_out, nullptr);
}